// Round 2
// baseline (91.584 us; speedup 1.0000x reference)
//
#include <hip/hip_runtime.h>
#include <stdint.h>

typedef __attribute__((ext_vector_type(8))) short short8;     // bf16x8 MFMA frag (4 VGPR)
typedef __attribute__((ext_vector_type(4))) float floatx4;
typedef __attribute__((ext_vector_type(4))) unsigned int uintx4;
typedef __attribute__((ext_vector_type(2))) unsigned int uintx2;

#define S_LEN 2048
#define NHEAD 16
#define DHEAD 64
#define QB    128
#define KB    64
#define NEGINF (-__builtin_inff())

static __device__ __forceinline__ unsigned f2bf(float f) {
    union { float f; unsigned u; } w; w.f = f;
    return (w.u + 0x7FFFu + ((w.u >> 16) & 1u)) >> 16;   // RNE f32->bf16 (no NaN in data)
}

static __device__ __forceinline__ floatx4 mfma16(short8 a, short8 b, floatx4 c) {
    return __builtin_amdgcn_mfma_f32_16x16x32_bf16(a, b, c, 0, 0, 0);
}

__global__ __launch_bounds__(512) void fa3_kernel(
    const float* __restrict__ qg,
    const float* __restrict__ kg,
    const float* __restrict__ vg,
    const int*   __restrict__ mg,          // bool mask arrives as int32
    float* __restrict__ og)
{
    // Qs/Ks: row-major [row][64] bf16, byte ^= (row&7)<<4
    // Vt:    TRANSPOSED [d=64][key=64] bf16, byte ^= (((d&7)^((d>>3)&7))<<4)
    __shared__ unsigned short Qs[QB * DHEAD];
    __shared__ unsigned short Ks[KB * DHEAD];
    __shared__ unsigned short Vt[DHEAD * KB];
    __shared__ float Ms[KB];

    const int tid  = threadIdx.x;
    const int bid  = blockIdx.x;
    const int qb   = 15 - (bid >> 5);        // heavy q-blocks first
    const int bh   = bid & 31;
    const int b    = bh >> 4;
    const int h    = bh & 15;
    const int w    = tid >> 6;               // wave 0..7 -> q-rows [16w,16w+16)
    const int lane = tid & 63;
    const int g    = lane >> 4;
    const int lm   = lane & 15;

    // ---------------- stage Q: load, L2-normalize * 0.125, bf16 -> Qs ----------------
    {
        const int r  = tid >> 2;             // 0..127 q-row
        const int q0 = tid & 3;              // 16-dim quarter
        const float* src = qg + (((size_t)b * S_LEN + (size_t)qb * QB + r) * NHEAD + h) * DHEAD + q0 * 16;
        floatx4 f0 = *(const floatx4*)(src + 0);
        floatx4 f1 = *(const floatx4*)(src + 4);
        floatx4 f2 = *(const floatx4*)(src + 8);
        floatx4 f3 = *(const floatx4*)(src + 12);
        float ssq = 0.f;
        #pragma unroll
        for (int i = 0; i < 4; ++i)
            ssq += f0[i]*f0[i] + f1[i]*f1[i] + f2[i]*f2[i] + f3[i]*f3[i];
        ssq += __shfl_xor(ssq, 1);
        ssq += __shfl_xor(ssq, 2);
        const float sc = 0.125f / fmaxf(sqrtf(ssq), 1e-12f);
        float fv[16];
        #pragma unroll
        for (int i = 0; i < 4; ++i) { fv[i]=f0[i]; fv[4+i]=f1[i]; fv[8+i]=f2[i]; fv[12+i]=f3[i]; }
        unsigned pk[8];
        #pragma unroll
        for (int i = 0; i < 8; ++i)
            pk[i] = f2bf(fv[2*i]*sc) | (f2bf(fv[2*i+1]*sc) << 16);
        const int X = (r & 7) << 4;
        char* qp = (char*)Qs + r * 128;
        *(uintx4*)(qp + ((32*q0)      ^ X)) = (uintx4){pk[0],pk[1],pk[2],pk[3]};
        *(uintx4*)(qp + ((32*q0 + 16) ^ X)) = (uintx4){pk[4],pk[5],pk[6],pk[7]};
    }
    __syncthreads();

    // per-lane Q fragment (B operand of swapped QK^T): this lane's column q = lm
    short8 qf[2];
    {
        const int row = w * 16 + lm;
        const int X = (row & 7) << 4;
        const char* base = (const char*)Qs + row * 128;
        #pragma unroll
        for (int ks = 0; ks < 2; ++ks) {
            union { short8 s; uintx2 u[2]; } u;
            u.u[0] = *(const uintx2*)(base + ((64*ks + 8*g)      ^ X));
            u.u[1] = *(const uintx2*)(base + ((64*ks + 8*g + 32) ^ X));
            qf[ks] = u.s;
        }
    }

    floatx4 oacc[4];
    #pragma unroll
    for (int nt = 0; nt < 4; ++nt) oacc[nt] = (floatx4){0.f,0.f,0.f,0.f};
    float mrun = NEGINF, lrun = 0.f;
    const int q_glob = qb * QB + w * 16 + lm;
    const int nkt = (qb == 0) ? 2 : (2 * qb + 2);   // first 128 queries attend keys [0,128) fully

    for (int kt = 0; kt < nkt; ++kt) {
        const int kb0 = kt * KB;
        // ---- stage K (row-major) and V (transposed) fp32->bf16, + mask ----
        {
            const int r = tid >> 3;          // key 0..63
            const int o = tid & 7;           // 8-dim octet
            const size_t goff = (((size_t)b * S_LEN + kb0 + r) * NHEAD + h) * DHEAD + o * 8;
            floatx4 a0 = *(const floatx4*)(kg + goff);
            floatx4 a1 = *(const floatx4*)(kg + goff + 4);
            floatx4 c0 = *(const floatx4*)(vg + goff);
            floatx4 c1 = *(const floatx4*)(vg + goff + 4);
            uintx4 kw = (uintx4){ f2bf(a0[0]) | (f2bf(a0[1])<<16),
                                  f2bf(a0[2]) | (f2bf(a0[3])<<16),
                                  f2bf(a1[0]) | (f2bf(a1[1])<<16),
                                  f2bf(a1[2]) | (f2bf(a1[3])<<16) };
            *(uintx4*)((char*)Ks + r*128 + ((16*o) ^ ((r & 7) << 4))) = kw;
            float cv[8];
            #pragma unroll
            for (int i = 0; i < 4; ++i) { cv[i] = c0[i]; cv[4+i] = c1[i]; }
            #pragma unroll
            for (int i = 0; i < 8; ++i) {
                const int d = 8*o + i;                       // d&7 == i, d>>3 == o
                Vt[d*64 + (r ^ (((i ^ o) & 7) << 3))] = (unsigned short)f2bf(cv[i]);
            }
            if (tid < KB) Ms[tid] = mg[(size_t)b * S_LEN + kb0 + tid] ? 0.f : NEGINF;
        }
        __syncthreads();

        // ---- swapped QK^T: S^T[key][q] = K · Q^T ----
        floatx4 st[4];
        #pragma unroll
        for (int mt = 0; mt < 4; ++mt) st[mt] = (floatx4){0.f,0.f,0.f,0.f};
        #pragma unroll
        for (int ks = 0; ks < 2; ++ks) {
            #pragma unroll
            for (int mt = 0; mt < 4; ++mt) {
                const int row = mt * 16 + lm;           // key row
                const int X = (row & 7) << 4;
                const char* base = (const char*)Ks + row * 128;
                union { short8 s; uintx2 u[2]; } u;
                u.u[0] = *(const uintx2*)(base + ((64*ks + 8*g)      ^ X));
                u.u[1] = *(const uintx2*)(base + ((64*ks + 8*g + 32) ^ X));
                st[mt] = mfma16(u.s, qf[ks], st[mt]);
            }
        }

        // ---- key-mask bias + causal (diagonal tiles only) ----
        const bool diag = (qb > 0) && (kt >= 2 * qb);
        float sv[16];
        #pragma unroll
        for (int mt = 0; mt < 4; ++mt) {
            #pragma unroll
            for (int j = 0; j < 4; ++j) {
                const int kl = mt * 16 + 4 * g + j;     // key within tile
                float s = st[mt][j] + Ms[kl];
                if (diag && (kb0 + kl > q_glob)) s = NEGINF;
                sv[mt * 4 + j] = s;
            }
        }

        // ---- online softmax; lane owns q-row lm (16 in-lane + xor16/32) ----
        float rmax = sv[0];
        #pragma unroll
        for (int i = 1; i < 16; ++i) rmax = fmaxf(rmax, sv[i]);
        rmax = fmaxf(rmax, __shfl_xor(rmax, 16));
        rmax = fmaxf(rmax, __shfl_xor(rmax, 32));
        const float mnew = fmaxf(mrun, rmax);
        const float cf = __expf(mrun - mnew);           // first tile: exp(-inf)=0
        float p[16], psum = 0.f;
        #pragma unroll
        for (int i = 0; i < 16; ++i) { p[i] = __expf(sv[i] - mnew); psum += p[i]; }
        psum += __shfl_xor(psum, 16);
        psum += __shfl_xor(psum, 32);
        lrun = lrun * cf + psum;
        mrun = mnew;

        // rescale O (O rows are q = 4g+j; cf for that q lives in any lane with lane&15==4g+j)
        float cj[4];
        #pragma unroll
        for (int j = 0; j < 4; ++j) cj[j] = __shfl(cf, 20 * g + j);
        #pragma unroll
        for (int nt = 0; nt < 4; ++nt)
            #pragma unroll
            for (int j = 0; j < 4; ++j) oacc[nt][j] *= cj[j];

        // P -> bf16 PV A-frags (S^T D-layout == A-frag key layout, zero movement)
        short8 pa[2];
        #pragma unroll
        for (int ks = 0; ks < 2; ++ks)
            #pragma unroll
            for (int i = 0; i < 8; ++i)
                pa[ks][i] = (short)f2bf(p[(2*ks + (i>>2))*4 + (i&3)]);

        // ---- PV: B-frag from transposed Vt, same read shape as qf ----
        #pragma unroll
        for (int nt = 0; nt < 4; ++nt) {
            const int d = 16 * nt + lm;
            const int xz = (((d & 7) ^ ((d >> 3) & 7)) & 7) << 4;
            const char* vb = (const char*)Vt + d * 128;
            #pragma unroll
            for (int ks = 0; ks < 2; ++ks) {
                union { short8 s; uintx2 u[2]; } vu;
                vu.u[0] = *(const uintx2*)(vb + ((64*ks + 8*g)      ^ xz));
                vu.u[1] = *(const uintx2*)(vb + ((64*ks + 8*g + 32) ^ xz));
                oacc[nt] = mfma16(pa[ks], vu.s, oacc[nt]);
            }
        }
        __syncthreads();
    }

    // ---- epilogue: O /= l, store fp32 ----
    const float inv = 1.0f / lrun;
    #pragma unroll
    for (int j = 0; j < 4; ++j) {
        const float invj = __shfl(inv, 20 * g + j);
        const int row = qb * QB + w * 16 + 4 * g + j;
        float* dst = og + (((size_t)b * S_LEN + row) * NHEAD + h) * DHEAD + lm;
        #pragma unroll
        for (int nt = 0; nt < 4; ++nt) dst[nt * 16] = oacc[nt][j] * invj;
    }
}

extern "C" void kernel_launch(void* const* d_in, const int* in_sizes, int n_in,
                              void* d_out, int out_size, void* d_ws, size_t ws_size,
                              hipStream_t stream)
{
    const float* q = (const float*)d_in[0];
    const float* k = (const float*)d_in[1];
    const float* v = (const float*)d_in[2];
    const int*   m = (const int*)d_in[3];
    float* out = (float*)d_out;
    (void)in_sizes; (void)n_in; (void)out_size; (void)d_ws; (void)ws_size;
    fa3_kernel<<<dim3(512), dim3(512), 0, stream>>>(q, k, v, m, out);
}

// Round 3
// 74.501 us; speedup vs baseline: 1.2293x; 1.2293x over previous
//
#include <hip/hip_runtime.h>
#include <stdint.h>

typedef __attribute__((ext_vector_type(8))) short short8;     // bf16x8 MFMA frag (4 VGPR)
typedef __attribute__((ext_vector_type(4))) float floatx4;
typedef __attribute__((ext_vector_type(4))) unsigned int uintx4;
typedef __attribute__((ext_vector_type(2))) unsigned int uintx2;

#define S_LEN 2048
#define NHEAD 16
#define DHEAD 64
#define QB    64
#define KB    64
#define NTILE 32                              // S_LEN / KB
#define PL_BYTES (S_LEN * DHEAD * 2)          // 262144 bf16 bytes per (b,h) plane
#define VOFF  (2 * NHEAD * PL_BYTES)          // 8388608
#define MOFF  (2 * VOFF)                      // 16777216
#define WS_NEEDED ((size_t)MOFF + 2 * NTILE * 8)
#define NEGINF (-__builtin_inff())

#define GLOAD_LDS16(gp, lp) \
    __builtin_amdgcn_global_load_lds((const __attribute__((address_space(1))) unsigned int*)(gp), \
                                     (__attribute__((address_space(3))) unsigned int*)(lp), 16, 0, 0)

static __device__ __forceinline__ unsigned f2bf(float f) {
    union { float f; unsigned u; } w; w.f = f;
    return (w.u + 0x7FFFu + ((w.u >> 16) & 1u)) >> 16;   // RNE f32->bf16 (no NaN in data)
}

static __device__ __forceinline__ floatx4 mfma16(short8 a, short8 b, floatx4 c) {
    return __builtin_amdgcn_mfma_f32_16x16x32_bf16(a, b, c, 0, 0, 0);
}

// ---------------------------------------------------------------------------
// Prepass: K -> bf16 row-major pre-swizzled; V -> bf16 TRANSPOSED [d][key]
// pre-swizzled (LDS tile transpose); mask -> u64 bitmask per (b, tile).
// Swizzle (both): byte ^= (row&7)<<4 within 128B rows.
// ---------------------------------------------------------------------------
__global__ __launch_bounds__(256) void prep_kernel(
    const float* __restrict__ kg, const float* __restrict__ vg,
    const int* __restrict__ mg, char* __restrict__ ws)
{
    __shared__ unsigned short Tl[64 * 72];    // transposed V tile, padded stride
    const int bid = blockIdx.x;               // 0..1023
    const int t   = bid & 31;                 // key tile
    const int bh  = bid >> 5;
    const int b   = bh >> 4, h = bh & 15;
    const int tid = threadIdx.x;
    char* kpre = ws + (size_t)bh * PL_BYTES;
    char* vpre = ws + VOFF + (size_t)bh * PL_BYTES;

    // K: convert + swizzled store (thread -> 32B of output)
    {
        const int r  = tid >> 2;              // key row in tile
        const int c0 = (tid & 3) * 32;
        const int X  = (r & 7) << 4;
        const size_t grow = (((size_t)b * S_LEN + t * 64 + r) * NHEAD + h) * DHEAD;
        #pragma unroll
        for (int cc = 0; cc < 2; ++cc) {
            const int c  = c0 + 16 * cc;
            const int d0 = (c ^ X) >> 1;
            floatx4 f0 = *(const floatx4*)(kg + grow + d0);
            floatx4 f1 = *(const floatx4*)(kg + grow + d0 + 4);
            uintx4 pk = (uintx4){ f2bf(f0[0]) | (f2bf(f0[1]) << 16),
                                  f2bf(f0[2]) | (f2bf(f0[3]) << 16),
                                  f2bf(f1[0]) | (f2bf(f1[1]) << 16),
                                  f2bf(f1[2]) | (f2bf(f1[3]) << 16) };
            *(uintx4*)(kpre + t * 8192 + r * 128 + c) = pk;
        }
    }
    // V: load rows coalesced, transpose into LDS
    {
        const int key = tid >> 2;
        const int d0  = (tid & 3) * 16;
        const size_t grow = (((size_t)b * S_LEN + t * 64 + key) * NHEAD + h) * DHEAD;
        #pragma unroll
        for (int q = 0; q < 4; ++q) {
            floatx4 f = *(const floatx4*)(vg + grow + d0 + 4 * q);
            #pragma unroll
            for (int ii = 0; ii < 4; ++ii)
                Tl[(d0 + 4 * q + ii) * 72 + key] = (unsigned short)f2bf(f[ii]);
        }
    }
    __syncthreads();
    // V out: swizzled 16B chunks of the transposed tile
    {
        const int d  = tid >> 2;
        const int c0 = (tid & 3) * 32;
        const int Xv = (d & 7) << 4;
        #pragma unroll
        for (int cc = 0; cc < 2; ++cc) {
            const int c  = c0 + 16 * cc;
            const int k0 = (c ^ Xv) >> 1;
            uintx4 pk = *(const uintx4*)(&Tl[d * 72 + k0]);
            *(uintx4*)(vpre + t * 8192 + d * 128 + c) = pk;
        }
    }
    // mask bits: one u64 per (b, tile)
    if (h == 0 && (tid >> 6) == 0) {
        unsigned long long bits = __ballot(mg[(size_t)b * S_LEN + t * 64 + (tid & 63)] != 0);
        if (tid == 0) *(unsigned long long*)(ws + MOFF + ((size_t)b * NTILE + t) * 8) = bits;
    }
}

// ---------------------------------------------------------------------------
// Main: 64 q-rows/block, 4 waves, double-buffered K/V via global_load_lds.
// ---------------------------------------------------------------------------
__global__ __launch_bounds__(256) void fa3_main(
    const float* __restrict__ qg, const char* __restrict__ ws,
    float* __restrict__ og)
{
    __shared__ unsigned short Qs[QB * DHEAD];        // 8 KB
    __shared__ unsigned short Ks[2][KB * DHEAD];     // 16 KB
    __shared__ unsigned short Vs[2][KB * DHEAD];     // 16 KB

    const int tid  = threadIdx.x;
    const int bid  = blockIdx.x;
    const int qb   = 31 - (bid >> 5);        // heavy q-blocks first
    const int bh   = bid & 31;
    const int b    = bh >> 4;
    const int h    = bh & 15;
    const int w    = tid >> 6;               // wave 0..3 -> q-rows [16w,16w+16)
    const int lane = tid & 63;
    const int g    = lane >> 4;
    const int lm   = lane & 15;
    const char* kpre = ws + (size_t)bh * PL_BYTES;
    const char* vpre = ws + VOFF + (size_t)bh * PL_BYTES;
    const unsigned long long* mbits = (const unsigned long long*)(ws + MOFF);
    const int nkt = (qb < 2) ? 2 : (qb + 1);

    // stage tile 0 (DMA overlaps the Q normalize below)
    {
        const int off = w * 1024 + lane * 16;
        #pragma unroll
        for (int rr = 0; rr < 2; ++rr) {
            GLOAD_LDS16(kpre + rr * 4096 + off, (char*)&Ks[0][0] + rr * 4096 + w * 1024);
            GLOAD_LDS16(vpre + rr * 4096 + off, (char*)&Vs[0][0] + rr * 4096 + w * 1024);
        }
    }

    // stage Q: load fp32, L2-normalize * 0.125, bf16, swizzled
    {
        const int r  = tid >> 2;             // 0..63 q-row
        const int q0 = tid & 3;
        const float* src = qg + (((size_t)b * S_LEN + (size_t)qb * QB + r) * NHEAD + h) * DHEAD + q0 * 16;
        floatx4 f0 = *(const floatx4*)(src + 0);
        floatx4 f1 = *(const floatx4*)(src + 4);
        floatx4 f2 = *(const floatx4*)(src + 8);
        floatx4 f3 = *(const floatx4*)(src + 12);
        float ssq = 0.f;
        #pragma unroll
        for (int i = 0; i < 4; ++i)
            ssq += f0[i]*f0[i] + f1[i]*f1[i] + f2[i]*f2[i] + f3[i]*f3[i];
        ssq += __shfl_xor(ssq, 1);
        ssq += __shfl_xor(ssq, 2);
        const float sc = 0.125f / fmaxf(sqrtf(ssq), 1e-12f);
        float fv[16];
        #pragma unroll
        for (int i = 0; i < 4; ++i) { fv[i]=f0[i]; fv[4+i]=f1[i]; fv[8+i]=f2[i]; fv[12+i]=f3[i]; }
        unsigned pk[8];
        #pragma unroll
        for (int i = 0; i < 8; ++i)
            pk[i] = f2bf(fv[2*i]*sc) | (f2bf(fv[2*i+1]*sc) << 16);
        const int X = (r & 7) << 4;
        char* qp = (char*)Qs + r * 128;
        *(uintx4*)(qp + ((32*q0)      ^ X)) = (uintx4){pk[0],pk[1],pk[2],pk[3]};
        *(uintx4*)(qp + ((32*q0 + 16) ^ X)) = (uintx4){pk[4],pk[5],pk[6],pk[7]};
    }
    asm volatile("s_waitcnt vmcnt(0)" ::: "memory");   // tile-0 DMA complete
    __syncthreads();                                    // Qs + tile 0 visible

    // per-lane Q fragment (B operand of swapped QK^T): column q = lm
    short8 qf[2];
    {
        const int row = w * 16 + lm;
        const int X = (row & 7) << 4;
        const char* base = (const char*)Qs + row * 128;
        #pragma unroll
        for (int ks = 0; ks < 2; ++ks) {
            union { short8 s; uintx2 u[2]; } u;
            u.u[0] = *(const uintx2*)(base + ((64*ks + 8*g)      ^ X));
            u.u[1] = *(const uintx2*)(base + ((64*ks + 8*g + 32) ^ X));
            qf[ks] = u.s;
        }
    }

    floatx4 oacc[4];
    #pragma unroll
    for (int nt = 0; nt < 4; ++nt) oacc[nt] = (floatx4){0.f,0.f,0.f,0.f};
    float mrun = NEGINF, lrun = 0.f;
    const int q_glob = qb * QB + w * 16 + lm;

    int cur = 0;
    for (int kt = 0; kt < nkt; ++kt) {
        // issue next tile's DMA (hidden under this tile's compute)
        if (kt + 1 < nkt) {
            const size_t tb = (size_t)(kt + 1) * 8192;
            const int off = w * 1024 + lane * 16;
            #pragma unroll
            for (int rr = 0; rr < 2; ++rr) {
                GLOAD_LDS16(kpre + tb + rr * 4096 + off, (char*)&Ks[cur ^ 1][0] + rr * 4096 + w * 1024);
                GLOAD_LDS16(vpre + tb + rr * 4096 + off, (char*)&Vs[cur ^ 1][0] + rr * 4096 + w * 1024);
            }
        }
        const unsigned long long mb = mbits[b * NTILE + kt];

        // ---- swapped QK^T: S^T[key][q] = K · Q^T ----
        floatx4 st[4];
        #pragma unroll
        for (int mt = 0; mt < 4; ++mt) st[mt] = (floatx4){0.f,0.f,0.f,0.f};
        #pragma unroll
        for (int ks = 0; ks < 2; ++ks) {
            #pragma unroll
            for (int mt = 0; mt < 4; ++mt) {
                const int row = mt * 16 + lm;           // key row
                const int X = (row & 7) << 4;
                const char* base = (const char*)Ks[cur] + row * 128;
                union { short8 s; uintx2 u[2]; } u;
                u.u[0] = *(const uintx2*)(base + ((64*ks + 8*g)      ^ X));
                u.u[1] = *(const uintx2*)(base + ((64*ks + 8*g + 32) ^ X));
                st[mt] = mfma16(u.s, qf[ks], st[mt]);
            }
        }

        // ---- key-pad mask (bit test) + causal (diagonal tile only) ----
        const bool diag = (qb >= 2) && (kt == qb);
        float sv[16];
        #pragma unroll
        for (int mt = 0; mt < 4; ++mt) {
            #pragma unroll
            for (int j = 0; j < 4; ++j) {
                const int kl = mt * 16 + 4 * g + j;     // key within tile
                float s = ((mb >> kl) & 1ull) ? st[mt][j] : NEGINF;
                if (diag && (kt * KB + kl > q_glob)) s = NEGINF;
                sv[mt * 4 + j] = s;
            }
        }

        // ---- online softmax; lane owns q-row lm ----
        float rmax = fmaxf(fmaxf(sv[0], sv[1]), fmaxf(sv[2], sv[3]));
        #pragma unroll
        for (int i = 4; i < 16; ++i) rmax = fmaxf(rmax, sv[i]);
        rmax = fmaxf(rmax, __shfl_xor(rmax, 16));
        rmax = fmaxf(rmax, __shfl_xor(rmax, 32));
        const float mnew = fmaxf(mrun, rmax);
        const float cf = __expf(mrun - mnew);           // first tile: exp(-inf)=0
        float p[16], psum = 0.f;
        #pragma unroll
        for (int i = 0; i < 16; ++i) { p[i] = __expf(sv[i] - mnew); psum += p[i]; }
        psum += __shfl_xor(psum, 16);
        psum += __shfl_xor(psum, 32);
        lrun = lrun * cf + psum;
        mrun = mnew;

        // rescale O (O rows are q = 4g+j; lane 20g+j has lane&15 == 4g+j)
        float cj[4];
        #pragma unroll
        for (int j = 0; j < 4; ++j) cj[j] = __shfl(cf, 20 * g + j);
        #pragma unroll
        for (int nt = 0; nt < 4; ++nt)
            #pragma unroll
            for (int j = 0; j < 4; ++j) oacc[nt][j] *= cj[j];

        // P -> bf16 PV A-frags (S^T D-layout == A-frag key layout)
        short8 pa[2];
        #pragma unroll
        for (int ks = 0; ks < 2; ++ks)
            #pragma unroll
            for (int i = 0; i < 8; ++i)
                pa[ks][i] = (short)f2bf(p[(2*ks + (i>>2))*4 + (i&3)]);

        // ---- PV from transposed Vs ----
        #pragma unroll
        for (int nt = 0; nt < 4; ++nt) {
            const int d = 16 * nt + lm;
            const int Xv = (d & 7) << 4;
            const char* vb = (const char*)Vs[cur] + d * 128;
            #pragma unroll
            for (int ks = 0; ks < 2; ++ks) {
                union { short8 s; uintx2 u[2]; } vu;
                vu.u[0] = *(const uintx2*)(vb + ((64*ks + 8*g)      ^ Xv));
                vu.u[1] = *(const uintx2*)(vb + ((64*ks + 8*g + 32) ^ Xv));
                oacc[nt] = mfma16(pa[ks], vu.s, oacc[nt]);
            }
        }

        asm volatile("s_waitcnt vmcnt(0)" ::: "memory");  // next tile's DMA done
        __syncthreads();
        cur ^= 1;
    }

    // ---- epilogue: O /= l, store fp32 ----
    const float inv = 1.0f / lrun;
    #pragma unroll
    for (int j = 0; j < 4; ++j) {
        const float invj = __shfl(inv, 20 * g + j);
        const int row = qb * QB + w * 16 + 4 * g + j;
        float* dst = og + (((size_t)b * S_LEN + row) * NHEAD + h) * DHEAD + lm;
        #pragma unroll
        for (int nt = 0; nt < 4; ++nt) dst[nt * 16] = oacc[nt][j] * invj;
    }
}

// ---------------------------------------------------------------------------
// Fallback (round-2 kernel, known-good) if ws_size is too small.
// ---------------------------------------------------------------------------
__global__ __launch_bounds__(512) void fa3_fallback(
    const float* __restrict__ qg, const float* __restrict__ kg,
    const float* __restrict__ vg, const int* __restrict__ mg,
    float* __restrict__ og)
{
    __shared__ unsigned short Qs[128 * DHEAD];
    __shared__ unsigned short Ks2[KB * DHEAD];
    __shared__ unsigned short Vt[DHEAD * KB];
    __shared__ float Ms[KB];

    const int tid  = threadIdx.x;
    const int bid  = blockIdx.x;
    const int qb   = 15 - (bid >> 5);
    const int bh   = bid & 31;
    const int b    = bh >> 4;
    const int h    = bh & 15;
    const int w    = tid >> 6;
    const int lane = tid & 63;
    const int g    = lane >> 4;
    const int lm   = lane & 15;

    {
        const int r  = tid >> 2;
        const int q0 = tid & 3;
        const float* src = qg + (((size_t)b * S_LEN + (size_t)qb * 128 + r) * NHEAD + h) * DHEAD + q0 * 16;
        floatx4 f0 = *(const floatx4*)(src + 0);
        floatx4 f1 = *(const floatx4*)(src + 4);
        floatx4 f2 = *(const floatx4*)(src + 8);
        floatx4 f3 = *(const floatx4*)(src + 12);
        float ssq = 0.f;
        #pragma unroll
        for (int i = 0; i < 4; ++i)
            ssq += f0[i]*f0[i] + f1[i]*f1[i] + f2[i]*f2[i] + f3[i]*f3[i];
        ssq += __shfl_xor(ssq, 1);
        ssq += __shfl_xor(ssq, 2);
        const float sc = 0.125f / fmaxf(sqrtf(ssq), 1e-12f);
        float fv[16];
        #pragma unroll
        for (int i = 0; i < 4; ++i) { fv[i]=f0[i]; fv[4+i]=f1[i]; fv[8+i]=f2[i]; fv[12+i]=f3[i]; }
        unsigned pk[8];
        #pragma unroll
        for (int i = 0; i < 8; ++i)
            pk[i] = f2bf(fv[2*i]*sc) | (f2bf(fv[2*i+1]*sc) << 16);
        const int X = (r & 7) << 4;
        char* qp = (char*)Qs + r * 128;
        *(uintx4*)(qp + ((32*q0)      ^ X)) = (uintx4){pk[0],pk[1],pk[2],pk[3]};
        *(uintx4*)(qp + ((32*q0 + 16) ^ X)) = (uintx4){pk[4],pk[5],pk[6],pk[7]};
    }
    __syncthreads();

    short8 qf[2];
    {
        const int row = w * 16 + lm;
        const int X = (row & 7) << 4;
        const char* base = (const char*)Qs + row * 128;
        #pragma unroll
        for (int ks = 0; ks < 2; ++ks) {
            union { short8 s; uintx2 u[2]; } u;
            u.u[0] = *(const uintx2*)(base + ((64*ks + 8*g)      ^ X));
            u.u[1] = *(const uintx2*)(base + ((64*ks + 8*g + 32) ^ X));
            qf[ks] = u.s;
        }
    }

    floatx4 oacc[4];
    #pragma unroll
    for (int nt = 0; nt < 4; ++nt) oacc[nt] = (floatx4){0.f,0.f,0.f,0.f};
    float mrun = NEGINF, lrun = 0.f;
    const int q_glob = qb * 128 + w * 16 + lm;
    const int nkt = (qb == 0) ? 2 : (2 * qb + 2);

    for (int kt = 0; kt < nkt; ++kt) {
        const int kb0 = kt * KB;
        {
            const int r = tid >> 3;
            const int o = tid & 7;
            const size_t goff = (((size_t)b * S_LEN + kb0 + r) * NHEAD + h) * DHEAD + o * 8;
            floatx4 a0 = *(const floatx4*)(kg + goff);
            floatx4 a1 = *(const floatx4*)(kg + goff + 4);
            floatx4 c0 = *(const floatx4*)(vg + goff);
            floatx4 c1 = *(const floatx4*)(vg + goff + 4);
            uintx4 kw = (uintx4){ f2bf(a0[0]) | (f2bf(a0[1])<<16),
                                  f2bf(a0[2]) | (f2bf(a0[3])<<16),
                                  f2bf(a1[0]) | (f2bf(a1[1])<<16),
                                  f2bf(a1[2]) | (f2bf(a1[3])<<16) };
            *(uintx4*)((char*)Ks2 + r*128 + ((16*o) ^ ((r & 7) << 4))) = kw;
            float cv[8];
            #pragma unroll
            for (int i = 0; i < 4; ++i) { cv[i] = c0[i]; cv[4+i] = c1[i]; }
            #pragma unroll
            for (int i = 0; i < 8; ++i) {
                const int d = 8*o + i;
                Vt[d*64 + (r ^ (((i ^ o) & 7) << 3))] = (unsigned short)f2bf(cv[i]);
            }
            if (tid < KB) Ms[tid] = mg[(size_t)b * S_LEN + kb0 + tid] ? 0.f : NEGINF;
        }
        __syncthreads();

        floatx4 st[4];
        #pragma unroll
        for (int mt = 0; mt < 4; ++mt) st[mt] = (floatx4){0.f,0.f,0.f,0.f};
        #pragma unroll
        for (int ks = 0; ks < 2; ++ks) {
            #pragma unroll
            for (int mt = 0; mt < 4; ++mt) {
                const int row = mt * 16 + lm;
                const int X = (row & 7) << 4;
                const char* base = (const char*)Ks2 + row * 128;
                union { short8 s; uintx2 u[2]; } u;
                u.u[0] = *(const uintx2*)(base + ((64*ks + 8*g)      ^ X));
                u.u[1] = *(const uintx2*)(base + ((64*ks + 8*g + 32) ^ X));
                st[mt] = mfma16(u.s, qf[ks], st[mt]);
            }
        }

        const bool diag = (qb > 0) && (kt >= 2 * qb);
        float sv[16];
        #pragma unroll
        for (int mt = 0; mt < 4; ++mt) {
            #pragma unroll
            for (int j = 0; j < 4; ++j) {
                const int kl = mt * 16 + 4 * g + j;
                float s = st[mt][j] + Ms[kl];
                if (diag && (kb0 + kl > q_glob)) s = NEGINF;
                sv[mt * 4 + j] = s;
            }
        }

        float rmax = sv[0];
        #pragma unroll
        for (int i = 1; i < 16; ++i) rmax = fmaxf(rmax, sv[i]);
        rmax = fmaxf(rmax, __shfl_xor(rmax, 16));
        rmax = fmaxf(rmax, __shfl_xor(rmax, 32));
        const float mnew = fmaxf(mrun, rmax);
        const float cf = __expf(mrun - mnew);
        float p[16], psum = 0.f;
        #pragma unroll
        for (int i = 0; i < 16; ++i) { p[i] = __expf(sv[i] - mnew); psum += p[i]; }
        psum += __shfl_xor(psum, 16);
        psum += __shfl_xor(psum, 32);
        lrun = lrun * cf + psum;
        mrun = mnew;

        float cj[4];
        #pragma unroll
        for (int j = 0; j < 4; ++j) cj[j] = __shfl(cf, 20 * g + j);
        #pragma unroll
        for (int nt = 0; nt < 4; ++nt)
            #pragma unroll
            for (int j = 0; j < 4; ++j) oacc[nt][j] *= cj[j];

        short8 pa[2];
        #pragma unroll
        for (int ks = 0; ks < 2; ++ks)
            #pragma unroll
            for (int i = 0; i < 8; ++i)
                pa[ks][i] = (short)f2bf(p[(2*ks + (i>>2))*4 + (i&3)]);

        #pragma unroll
        for (int nt = 0; nt < 4; ++nt) {
            const int d = 16 * nt + lm;
            const int xz = (((d & 7) ^ ((d >> 3) & 7)) & 7) << 4;
            const char* vb = (const char*)Vt + d * 128;
            #pragma unroll
            for (int ks = 0; ks < 2; ++ks) {
                union { short8 s; uintx2 u[2]; } vu;
                vu.u[0] = *(const uintx2*)(vb + ((64*ks + 8*g)      ^ xz));
                vu.u[1] = *(const uintx2*)(vb + ((64*ks + 8*g + 32) ^ xz));
                oacc[nt] = mfma16(pa[ks], vu.s, oacc[nt]);
            }
        }
        __syncthreads();
    }

    const float inv = 1.0f / lrun;
    #pragma unroll
    for (int j = 0; j < 4; ++j) {
        const float invj = __shfl(inv, 20 * g + j);
        const int row = qb * 128 + w * 16 + 4 * g + j;
        float* dst = og + (((size_t)b * S_LEN + row) * NHEAD + h) * DHEAD + lm;
        #pragma unroll
        for (int nt = 0; nt < 4; ++nt) dst[nt * 16] = oacc[nt][j] * invj;
    }
}

extern "C" void kernel_launch(void* const* d_in, const int* in_sizes, int n_in,
                              void* d_out, int out_size, void* d_ws, size_t ws_size,
                              hipStream_t stream)
{
    const float* q = (const float*)d_in[0];
    const float* k = (const float*)d_in[1];
    const float* v = (const float*)d_in[2];
    const int*   m = (const int*)d_in[3];
    float* out = (float*)d_out;
    (void)in_sizes; (void)n_in; (void)out_size;
    if (ws_size >= WS_NEEDED) {
        prep_kernel<<<dim3(1024), dim3(256), 0, stream>>>(k, v, m, (char*)d_ws);
        fa3_main<<<dim3(1024), dim3(256), 0, stream>>>(q, (const char*)d_ws, out);
    } else {
        fa3_fallback<<<dim3(512), dim3(512), 0, stream>>>(q, k, v, m, out);
    }
}

// Round 4
// 67.659 us; speedup vs baseline: 1.3536x; 1.1011x over previous
//
#include <hip/hip_runtime.h>
#include <stdint.h>

typedef __attribute__((ext_vector_type(8))) short short8;     // bf16x8 MFMA frag (4 VGPR)
typedef __attribute__((ext_vector_type(4))) float floatx4;
typedef __attribute__((ext_vector_type(4))) unsigned int uintx4;
typedef __attribute__((ext_vector_type(2))) unsigned int uintx2;

#define S_LEN 2048
#define NHEAD 16
#define DHEAD 64
#define QB    64
#define KB    64
#define NTILE 32                              // S_LEN / KB
#define PL_BYTES (S_LEN * DHEAD * 2)          // 262144 bf16 bytes per (b,h) plane
#define VOFF  (2 * NHEAD * PL_BYTES)          // 8388608
#define MOFF  (2 * VOFF)                      // 16777216
#define WS_NEEDED ((size_t)MOFF + 2 * NTILE * 8)
#define NEGINF (-__builtin_inff())
#define LOG2E 1.4426950408889634f

#define GLOAD_LDS16(gp, lp) \
    __builtin_amdgcn_global_load_lds((const __attribute__((address_space(1))) unsigned int*)(gp), \
                                     (__attribute__((address_space(3))) unsigned int*)(lp), 16, 0, 0)

static __device__ __forceinline__ unsigned f2bf(float f) {
    union { float f; unsigned u; } w; w.f = f;
    return (w.u + 0x7FFFu + ((w.u >> 16) & 1u)) >> 16;   // RNE f32->bf16 (no NaN in data)
}

static __device__ __forceinline__ unsigned cvtpk(float lo, float hi) {
    unsigned r;
    asm("v_cvt_pk_bf16_f32 %0, %1, %2" : "=v"(r) : "v"(lo), "v"(hi));
    return r;                                             // [hi_bf16 | lo_bf16]
}

static __device__ __forceinline__ floatx4 mfma16(short8 a, short8 b, floatx4 c) {
    return __builtin_amdgcn_mfma_f32_16x16x32_bf16(a, b, c, 0, 0, 0);
}

// ---------------------------------------------------------------------------
// Prepass: K -> bf16 row-major pre-swizzled; V -> bf16 TRANSPOSED [d][pkey]
// with per-32 key interleave (p=8a+i -> key 16(i>>2)+4a+(i&3)) so the main
// kernel's PV B-fragment is one contiguous ds_read_b128. Mask -> u64 bits.
// Swizzle (both planes): byte ^= (row&7)<<4 within 128B rows.
// ---------------------------------------------------------------------------
__global__ __launch_bounds__(256) void prep_kernel(
    const float* __restrict__ kg, const float* __restrict__ vg,
    const int* __restrict__ mg, char* __restrict__ ws)
{
    __shared__ unsigned short Tl[64 * 72];    // transposed V tile, padded stride
    const int bid = blockIdx.x;               // 0..1023
    const int t   = bid & 31;                 // key tile
    const int bh  = bid >> 5;
    const int b   = bh >> 4, h = bh & 15;
    const int tid = threadIdx.x;
    char* kpre = ws + (size_t)bh * PL_BYTES;
    char* vpre = ws + VOFF + (size_t)bh * PL_BYTES;

    // K: convert + swizzled store (thread -> 32B of output)
    {
        const int r  = tid >> 2;              // key row in tile
        const int c0 = (tid & 3) * 32;
        const int X  = (r & 7) << 4;
        const size_t grow = (((size_t)b * S_LEN + t * 64 + r) * NHEAD + h) * DHEAD;
        #pragma unroll
        for (int cc = 0; cc < 2; ++cc) {
            const int c  = c0 + 16 * cc;
            const int d0 = (c ^ X) >> 1;
            floatx4 f0 = *(const floatx4*)(kg + grow + d0);
            floatx4 f1 = *(const floatx4*)(kg + grow + d0 + 4);
            uintx4 pk = (uintx4){ f2bf(f0[0]) | (f2bf(f0[1]) << 16),
                                  f2bf(f0[2]) | (f2bf(f0[3]) << 16),
                                  f2bf(f1[0]) | (f2bf(f1[1]) << 16),
                                  f2bf(f1[2]) | (f2bf(f1[3]) << 16) };
            *(uintx4*)(kpre + t * 8192 + r * 128 + c) = pk;
        }
    }
    // V: load rows coalesced, transpose into LDS
    {
        const int key = tid >> 2;
        const int d0  = (tid & 3) * 16;
        const size_t grow = (((size_t)b * S_LEN + t * 64 + key) * NHEAD + h) * DHEAD;
        #pragma unroll
        for (int q = 0; q < 4; ++q) {
            floatx4 f = *(const floatx4*)(vg + grow + d0 + 4 * q);
            #pragma unroll
            for (int ii = 0; ii < 4; ++ii)
                Tl[(d0 + 4 * q + ii) * 72 + key] = (unsigned short)f2bf(f[ii]);
        }
    }
    __syncthreads();
    // V out: swizzled 16B chunks, keys gathered in interleaved storage order
    {
        const int d  = tid >> 2;
        const int c0 = (tid & 3) * 32;
        const int Xv = (d & 7) << 4;
        #pragma unroll
        for (int cc = 0; cc < 2; ++cc) {
            const int c   = c0 + 16 * cc;      // physical byte pos in 128B row
            const int pp0 = (c ^ Xv) >> 1;     // logical halfword pos (mult of 8)
            const int blk = pp0 >> 5;
            const int a   = (pp0 & 31) >> 3;
            unsigned short vals[8];
            #pragma unroll
            for (int i = 0; i < 8; ++i) {
                const int key = 32 * blk + ((i < 4) ? (4 * a + i) : (16 + 4 * a + i - 4));
                vals[i] = Tl[d * 72 + key];
            }
            *(uintx4*)(vpre + t * 8192 + d * 128 + c) = *(const uintx4*)vals;
        }
    }
    // mask bits: one u64 per (b, tile)
    if (h == 0 && (tid >> 6) == 0) {
        unsigned long long bits = __ballot(mg[(size_t)b * S_LEN + t * 64 + (tid & 63)] != 0);
        if (tid == 0) *(unsigned long long*)(ws + MOFF + ((size_t)b * NTILE + t) * 8) = bits;
    }
}

// ---------------------------------------------------------------------------
// Main: 64 q-rows/block, 4 waves, double-buffered K/V via global_load_lds,
// all fragment reads single ds_read_b128, exp2-domain softmax, cvt_pk pa.
// ---------------------------------------------------------------------------
__global__ __launch_bounds__(256) void fa3_main(
    const float* __restrict__ qg, const char* __restrict__ ws,
    float* __restrict__ og)
{
    __shared__ unsigned short Qs[QB * DHEAD];        // 8 KB
    __shared__ unsigned short Ks[2][KB * DHEAD];     // 16 KB
    __shared__ unsigned short Vs[2][KB * DHEAD];     // 16 KB

    const int tid  = threadIdx.x;
    const int bid  = blockIdx.x;
    const int qb   = 31 - (bid >> 5);        // heavy q-blocks first
    const int bh   = bid & 31;
    const int b    = bh >> 4;
    const int h    = bh & 15;
    const int w    = tid >> 6;               // wave 0..3 -> q-rows [16w,16w+16)
    const int lane = tid & 63;
    const int g    = lane >> 4;
    const int lm   = lane & 15;
    const char* kpre = ws + (size_t)bh * PL_BYTES;
    const char* vpre = ws + VOFF + (size_t)bh * PL_BYTES;
    const unsigned long long* mbits = (const unsigned long long*)(ws + MOFF);
    const int nkt = (qb < 2) ? 2 : (qb + 1);

    // stage tile 0 (DMA overlaps the Q normalize below)
    {
        const int off = w * 1024 + lane * 16;
        #pragma unroll
        for (int rr = 0; rr < 2; ++rr) {
            GLOAD_LDS16(kpre + rr * 4096 + off, (char*)&Ks[0][0] + rr * 4096 + w * 1024);
            GLOAD_LDS16(vpre + rr * 4096 + off, (char*)&Vs[0][0] + rr * 4096 + w * 1024);
        }
    }

    // stage Q: load fp32, L2-normalize * 0.125 * log2(e), bf16, swizzled
    {
        const int r  = tid >> 2;             // 0..63 q-row
        const int q0 = tid & 3;
        const float* src = qg + (((size_t)b * S_LEN + (size_t)qb * QB + r) * NHEAD + h) * DHEAD + q0 * 16;
        floatx4 f0 = *(const floatx4*)(src + 0);
        floatx4 f1 = *(const floatx4*)(src + 4);
        floatx4 f2 = *(const floatx4*)(src + 8);
        floatx4 f3 = *(const floatx4*)(src + 12);
        float ssq = 0.f;
        #pragma unroll
        for (int i = 0; i < 4; ++i)
            ssq += f0[i]*f0[i] + f1[i]*f1[i] + f2[i]*f2[i] + f3[i]*f3[i];
        ssq += __shfl_xor(ssq, 1);
        ssq += __shfl_xor(ssq, 2);
        const float sc = (0.125f * LOG2E) / fmaxf(sqrtf(ssq), 1e-12f);
        float fv[16];
        #pragma unroll
        for (int i = 0; i < 4; ++i) { fv[i]=f0[i]; fv[4+i]=f1[i]; fv[8+i]=f2[i]; fv[12+i]=f3[i]; }
        unsigned pk[8];
        #pragma unroll
        for (int i = 0; i < 8; ++i)
            pk[i] = cvtpk(fv[2*i]*sc, fv[2*i+1]*sc);
        const int X = (r & 7) << 4;
        char* qp = (char*)Qs + r * 128;
        *(uintx4*)(qp + ((32*q0)      ^ X)) = (uintx4){pk[0],pk[1],pk[2],pk[3]};
        *(uintx4*)(qp + ((32*q0 + 16) ^ X)) = (uintx4){pk[4],pk[5],pk[6],pk[7]};
    }
    asm volatile("s_waitcnt vmcnt(0)" ::: "memory");   // tile-0 DMA complete
    __syncthreads();                                    // Qs + tile 0 visible

    // per-lane Q fragment (B operand of swapped QK^T): column q = lm,
    // contiguous k-map (d = 32ks + 8g + i), single b128 per ks
    short8 qf[2];
    {
        const int row = w * 16 + lm;
        const int X = (row & 7) << 4;
        const char* base = (const char*)Qs + row * 128;
        #pragma unroll
        for (int ks = 0; ks < 2; ++ks)
            qf[ks] = *(const short8*)(base + ((64*ks + 16*g) ^ X));
    }

    floatx4 oacc[4];
    #pragma unroll
    for (int nt = 0; nt < 4; ++nt) oacc[nt] = (floatx4){0.f,0.f,0.f,0.f};
    float mrun = NEGINF, lrun = 0.f;
    const int q_glob = qb * QB + w * 16 + lm;

    int cur = 0;
    for (int kt = 0; kt < nkt; ++kt) {
        // issue next tile's DMA (hidden under this tile's compute)
        if (kt + 1 < nkt) {
            const size_t tb = (size_t)(kt + 1) * 8192;
            const int off = w * 1024 + lane * 16;
            #pragma unroll
            for (int rr = 0; rr < 2; ++rr) {
                GLOAD_LDS16(kpre + tb + rr * 4096 + off, (char*)&Ks[cur ^ 1][0] + rr * 4096 + w * 1024);
                GLOAD_LDS16(vpre + tb + rr * 4096 + off, (char*)&Vs[cur ^ 1][0] + rr * 4096 + w * 1024);
            }
        }
        const unsigned long long mb = mbits[b * NTILE + kt];

        // ---- swapped QK^T: S^T[key][q] = K · Q^T, single b128 per frag ----
        floatx4 st[4];
        #pragma unroll
        for (int mt = 0; mt < 4; ++mt) st[mt] = (floatx4){0.f,0.f,0.f,0.f};
        const int Xl = (lm & 7) << 4;
        const char* kbase = (const char*)Ks[cur] + lm * 128;
        __builtin_amdgcn_s_setprio(1);
        #pragma unroll
        for (int ks = 0; ks < 2; ++ks) {
            #pragma unroll
            for (int mt = 0; mt < 4; ++mt) {
                short8 kf = *(const short8*)(kbase + mt * 2048 + ((64*ks + 16*g) ^ Xl));
                st[mt] = mfma16(kf, qf[ks], st[mt]);
            }
        }
        __builtin_amdgcn_s_setprio(0);

        // ---- V B-frags early (latency hides under softmax VALU) ----
        short8 vf[4][2];
        {
            const char* vbase = (const char*)Vs[cur] + lm * 128;
            #pragma unroll
            for (int nt = 0; nt < 4; ++nt)
                #pragma unroll
                for (int ks = 0; ks < 2; ++ks)
                    vf[nt][ks] = *(const short8*)(vbase + nt * 2048 + ((64*ks + 16*g) ^ Xl));
        }

        // ---- key-pad mask (bit test) + causal (diagonal tile only) ----
        const bool diag = (qb >= 2) && (kt == qb);
        float sv[16];
        #pragma unroll
        for (int mt = 0; mt < 4; ++mt) {
            #pragma unroll
            for (int j = 0; j < 4; ++j) {
                const int kl = mt * 16 + 4 * g + j;     // key within tile
                float s = ((mb >> kl) & 1ull) ? st[mt][j] : NEGINF;
                if (diag && (kt * KB + kl > q_glob)) s = NEGINF;
                sv[mt * 4 + j] = s;
            }
        }

        // ---- online softmax (log2 domain); lane owns q-row lm ----
        float rmax = fmaxf(fmaxf(sv[0], sv[1]), fmaxf(sv[2], sv[3]));
        #pragma unroll
        for (int i = 4; i < 16; ++i) rmax = fmaxf(rmax, sv[i]);
        rmax = fmaxf(rmax, __shfl_xor(rmax, 16));
        rmax = fmaxf(rmax, __shfl_xor(rmax, 32));
        const float mnew = fmaxf(mrun, rmax);
        const float cf = exp2f(mrun - mnew);            // first tile: exp2(-inf)=0
        float p[16], psum = 0.f;
        #pragma unroll
        for (int i = 0; i < 16; ++i) { p[i] = exp2f(sv[i] - mnew); psum += p[i]; }
        psum += __shfl_xor(psum, 16);
        psum += __shfl_xor(psum, 32);
        lrun = lrun * cf + psum;
        mrun = mnew;

        // rescale O (O rows are q = 4g+j; lane 20g+j has lane&15 == 4g+j)
        float cj[4];
        #pragma unroll
        for (int j = 0; j < 4; ++j) cj[j] = __shfl(cf, 20 * g + j);
        #pragma unroll
        for (int nt = 0; nt < 4; ++nt)
            #pragma unroll
            for (int j = 0; j < 4; ++j) oacc[nt][j] *= cj[j];

        // P -> bf16 PV A-frags via v_cvt_pk (pairs are adjacent p indices)
        short8 pa[2];
        #pragma unroll
        for (int ks = 0; ks < 2; ++ks) {
            union { short8 s; uintx4 u; } pu;
            pu.u = (uintx4){ cvtpk(p[8*ks+0], p[8*ks+1]),
                             cvtpk(p[8*ks+2], p[8*ks+3]),
                             cvtpk(p[8*ks+4], p[8*ks+5]),
                             cvtpk(p[8*ks+6], p[8*ks+7]) };
            pa[ks] = pu.s;
        }

        // ---- PV (V storage key-interleave matches pa layout) ----
        __builtin_amdgcn_s_setprio(1);
        #pragma unroll
        for (int nt = 0; nt < 4; ++nt) {
            oacc[nt] = mfma16(pa[0], vf[nt][0], oacc[nt]);
            oacc[nt] = mfma16(pa[1], vf[nt][1], oacc[nt]);
        }
        __builtin_amdgcn_s_setprio(0);

        asm volatile("s_waitcnt vmcnt(0)" ::: "memory");  // next tile's DMA done
        __syncthreads();
        cur ^= 1;
    }

    // ---- epilogue: O /= l, store fp32 ----
    const float inv = 1.0f / lrun;
    #pragma unroll
    for (int j = 0; j < 4; ++j) {
        const float invj = __shfl(inv, 20 * g + j);
        const int row = qb * QB + w * 16 + 4 * g + j;
        float* dst = og + (((size_t)b * S_LEN + row) * NHEAD + h) * DHEAD + lm;
        #pragma unroll
        for (int nt = 0; nt < 4; ++nt) dst[nt * 16] = oacc[nt][j] * invj;
    }
}

// ---------------------------------------------------------------------------
// Fallback (round-2 kernel, known-good) if ws_size is too small.
// ---------------------------------------------------------------------------
__global__ __launch_bounds__(512) void fa3_fallback(
    const float* __restrict__ qg, const float* __restrict__ kg,
    const float* __restrict__ vg, const int* __restrict__ mg,
    float* __restrict__ og)
{
    __shared__ unsigned short Qs[128 * DHEAD];
    __shared__ unsigned short Ks2[KB * DHEAD];
    __shared__ unsigned short Vt[DHEAD * KB];
    __shared__ float Ms[KB];

    const int tid  = threadIdx.x;
    const int bid  = blockIdx.x;
    const int qb   = 15 - (bid >> 5);
    const int bh   = bid & 31;
    const int b    = bh >> 4;
    const int h    = bh & 15;
    const int w    = tid >> 6;
    const int lane = tid & 63;
    const int g    = lane >> 4;
    const int lm   = lane & 15;

    {
        const int r  = tid >> 2;
        const int q0 = tid & 3;
        const float* src = qg + (((size_t)b * S_LEN + (size_t)qb * 128 + r) * NHEAD + h) * DHEAD + q0 * 16;
        floatx4 f0 = *(const floatx4*)(src + 0);
        floatx4 f1 = *(const floatx4*)(src + 4);
        floatx4 f2 = *(const floatx4*)(src + 8);
        floatx4 f3 = *(const floatx4*)(src + 12);
        float ssq = 0.f;
        #pragma unroll
        for (int i = 0; i < 4; ++i)
            ssq += f0[i]*f0[i] + f1[i]*f1[i] + f2[i]*f2[i] + f3[i]*f3[i];
        ssq += __shfl_xor(ssq, 1);
        ssq += __shfl_xor(ssq, 2);
        const float sc = 0.125f / fmaxf(sqrtf(ssq), 1e-12f);
        float fv[16];
        #pragma unroll
        for (int i = 0; i < 4; ++i) { fv[i]=f0[i]; fv[4+i]=f1[i]; fv[8+i]=f2[i]; fv[12+i]=f3[i]; }
        unsigned pk[8];
        #pragma unroll
        for (int i = 0; i < 8; ++i)
            pk[i] = f2bf(fv[2*i]*sc) | (f2bf(fv[2*i+1]*sc) << 16);
        const int X = (r & 7) << 4;
        char* qp = (char*)Qs + r * 128;
        *(uintx4*)(qp + ((32*q0)      ^ X)) = (uintx4){pk[0],pk[1],pk[2],pk[3]};
        *(uintx4*)(qp + ((32*q0 + 16) ^ X)) = (uintx4){pk[4],pk[5],pk[6],pk[7]};
    }
    __syncthreads();

    short8 qf[2];
    {
        const int row = w * 16 + lm;
        const int X = (row & 7) << 4;
        const char* base = (const char*)Qs + row * 128;
        #pragma unroll
        for (int ks = 0; ks < 2; ++ks) {
            union { short8 s; uintx2 u[2]; } u;
            u.u[0] = *(const uintx2*)(base + ((64*ks + 8*g)      ^ X));
            u.u[1] = *(const uintx2*)(base + ((64*ks + 8*g + 32) ^ X));
            qf[ks] = u.s;
        }
    }

    floatx4 oacc[4];
    #pragma unroll
    for (int nt = 0; nt < 4; ++nt) oacc[nt] = (floatx4){0.f,0.f,0.f,0.f};
    float mrun = NEGINF, lrun = 0.f;
    const int q_glob = qb * 128 + w * 16 + lm;
    const int nkt = (qb == 0) ? 2 : (2 * qb + 2);

    for (int kt = 0; kt < nkt; ++kt) {
        const int kb0 = kt * KB;
        {
            const int r = tid >> 3;
            const int o = tid & 7;
            const size_t goff = (((size_t)b * S_LEN + kb0 + r) * NHEAD + h) * DHEAD + o * 8;
            floatx4 a0 = *(const floatx4*)(kg + goff);
            floatx4 a1 = *(const floatx4*)(kg + goff + 4);
            floatx4 c0 = *(const floatx4*)(vg + goff);
            floatx4 c1 = *(const floatx4*)(vg + goff + 4);
            uintx4 kw = (uintx4){ f2bf(a0[0]) | (f2bf(a0[1])<<16),
                                  f2bf(a0[2]) | (f2bf(a0[3])<<16),
                                  f2bf(a1[0]) | (f2bf(a1[1])<<16),
                                  f2bf(a1[2]) | (f2bf(a1[3])<<16) };
            *(uintx4*)((char*)Ks2 + r*128 + ((16*o) ^ ((r & 7) << 4))) = kw;
            float cv[8];
            #pragma unroll
            for (int i = 0; i < 4; ++i) { cv[i] = c0[i]; cv[4+i] = c1[i]; }
            #pragma unroll
            for (int i = 0; i < 8; ++i) {
                const int d = 8*o + i;
                Vt[d*64 + (r ^ (((i ^ o) & 7) << 3))] = (unsigned short)f2bf(cv[i]);
            }
            if (tid < KB) Ms[tid] = mg[(size_t)b * S_LEN + kb0 + tid] ? 0.f : NEGINF;
        }
        __syncthreads();

        floatx4 st[4];
        #pragma unroll
        for (int mt = 0; mt < 4; ++mt) st[mt] = (floatx4){0.f,0.f,0.f,0.f};
        #pragma unroll
        for (int ks = 0; ks < 2; ++ks) {
            #pragma unroll
            for (int mt = 0; mt < 4; ++mt) {
                const int row = mt * 16 + lm;
                const int X = (row & 7) << 4;
                const char* base = (const char*)Ks2 + row * 128;
                union { short8 s; uintx2 u[2]; } u;
                u.u[0] = *(const uintx2*)(base + ((64*ks + 8*g)      ^ X));
                u.u[1] = *(const uintx2*)(base + ((64*ks + 8*g + 32) ^ X));
                st[mt] = mfma16(u.s, qf[ks], st[mt]);
            }
        }

        const bool diag = (qb > 0) && (kt >= 2 * qb);
        float sv[16];
        #pragma unroll
        for (int mt = 0; mt < 4; ++mt) {
            #pragma unroll
            for (int j = 0; j < 4; ++j) {
                const int kl = mt * 16 + 4 * g + j;
                float s = st[mt][j] + Ms[kl];
                if (diag && (kb0 + kl > q_glob)) s = NEGINF;
                sv[mt * 4 + j] = s;
            }
        }

        float rmax = sv[0];
        #pragma unroll
        for (int i = 1; i < 16; ++i) rmax = fmaxf(rmax, sv[i]);
        rmax = fmaxf(rmax, __shfl_xor(rmax, 16));
        rmax = fmaxf(rmax, __shfl_xor(rmax, 32));
        const float mnew = fmaxf(mrun, rmax);
        const float cf = __expf(mrun - mnew);
        float p[16], psum = 0.f;
        #pragma unroll
        for (int i = 0; i < 16; ++i) { p[i] = __expf(sv[i] - mnew); psum += p[i]; }
        psum += __shfl_xor(psum, 16);
        psum += __shfl_xor(psum, 32);
        lrun = lrun * cf + psum;
        mrun = mnew;

        float cj[4];
        #pragma unroll
        for (int j = 0; j < 4; ++j) cj[j] = __shfl(cf, 20 * g + j);
        #pragma unroll
        for (int nt = 0; nt < 4; ++nt)
            #pragma unroll
            for (int j = 0; j < 4; ++j) oacc[nt][j] *= cj[j];

        short8 pa[2];
        #pragma unroll
        for (int ks = 0; ks < 2; ++ks)
            #pragma unroll
            for (int i = 0; i < 8; ++i)
                pa[ks][i] = (short)f2bf(p[(2*ks + (i>>2))*4 + (i&3)]);

        #pragma unroll
        for (int nt = 0; nt < 4; ++nt) {
            const int d = 16 * nt + lm;
            const int xz = (((d & 7) ^ ((d >> 3) & 7)) & 7) << 4;
            const char* vb = (const char*)Vt + d * 128;
            #pragma unroll
            for (int ks = 0; ks < 2; ++ks) {
                union { short8 s; uintx2 u[2]; } vu;
                vu.u[0] = *(const uintx2*)(vb + ((64*ks + 8*g)      ^ xz));
                vu.u[1] = *(const uintx2*)(vb + ((64*ks + 8*g + 32) ^ xz));
                oacc[nt] = mfma16(pa[ks], vu.s, oacc[nt]);
            }
        }
        __syncthreads();
    }

    const float inv = 1.0f / lrun;
    #pragma unroll
    for (int j = 0; j < 4; ++j) {
        const float invj = __shfl(inv, 20 * g + j);
        const int row = qb * 128 + w * 16 + 4 * g + j;
        float* dst = og + (((size_t)b * S_LEN + row) * NHEAD + h) * DHEAD + lm;
        #pragma unroll
        for (int nt = 0; nt < 4; ++nt) dst[nt * 16] = oacc[nt][j] * invj;
    }
}

extern "C" void kernel_launch(void* const* d_in, const int* in_sizes, int n_in,
                              void* d_out, int out_size, void* d_ws, size_t ws_size,
                              hipStream_t stream)
{
    const float* q = (const float*)d_in[0];
    const float* k = (const float*)d_in[1];
    const float* v = (const float*)d_in[2];
    const int*   m = (const int*)d_in[3];
    float* out = (float*)d_out;
    (void)in_sizes; (void)n_in; (void)out_size;
    if (ws_size >= WS_NEEDED) {
        prep_kernel<<<dim3(1024), dim3(256), 0, stream>>>(k, v, m, (char*)d_ws);
        fa3_main<<<dim3(1024), dim3(256), 0, stream>>>(q, (const char*)d_ws, out);
    } else {
        fa3_fallback<<<dim3(512), dim3(512), 0, stream>>>(q, k, v, m, out);
    }
}

// Round 5
// 64.790 us; speedup vs baseline: 1.4135x; 1.0443x over previous
//
#include <hip/hip_runtime.h>
#include <stdint.h>

typedef __attribute__((ext_vector_type(8))) short short8;     // bf16x8 MFMA frag (4 VGPR)
typedef __attribute__((ext_vector_type(4))) float floatx4;
typedef __attribute__((ext_vector_type(4))) unsigned int uintx4;
typedef __attribute__((ext_vector_type(2))) unsigned int uintx2;

#define S_LEN 2048
#define NHEAD 16
#define DHEAD 64
#define KB    64
#define NTILE 32                              // S_LEN / KB
#define PL_BYTES (S_LEN * DHEAD * 2)          // 262144 bf16 bytes per (b,h) plane
#define VOFF  (2 * NHEAD * PL_BYTES)          // 8388608
#define MOFF  (2 * VOFF)                      // 16777216  (mask frags: 2 b x 4096 B)
#define WS_NEEDED ((size_t)MOFF + 2 * 4096)
#define NEGINF (-__builtin_inff())
#define LOG2E 1.4426950408889634f

#define GLOAD_LDS16(gp, lp) \
    __builtin_amdgcn_global_load_lds((const __attribute__((address_space(1))) unsigned int*)(gp), \
                                     (__attribute__((address_space(3))) unsigned int*)(lp), 16, 0, 0)

static __device__ __forceinline__ unsigned f2bf(float f) {
    union { float f; unsigned u; } w; w.f = f;
    return (w.u + 0x7FFFu + ((w.u >> 16) & 1u)) >> 16;   // RNE f32->bf16
}

static __device__ __forceinline__ unsigned cvtpk(float lo, float hi) {
    unsigned r;
    asm("v_cvt_pk_bf16_f32 %0, %1, %2" : "=v"(r) : "v"(lo), "v"(hi));
    return r;                                             // [hi_bf16 | lo_bf16]
}

static __device__ __forceinline__ floatx4 mfma16(short8 a, short8 b, floatx4 c) {
    return __builtin_amdgcn_mfma_f32_16x16x32_bf16(a, b, c, 0, 0, 0);
}

// ---------------------------------------------------------------------------
// Prepass: K -> bf16 row-major pre-swizzled; V -> bf16 TRANSPOSED [d][pkey]
// (per-32 key interleave p=8a+i -> key 16(i>>2)+4a+(i&3)), pad-masked V rows
// ZEROED; mask -> bf16 0/1 vector in PV-fragment order (128 B per (b,tile)).
// Swizzle (K,V planes): byte ^= (row&7)<<4 within 128B rows.
// ---------------------------------------------------------------------------
__global__ __launch_bounds__(256) void prep_kernel(
    const float* __restrict__ kg, const float* __restrict__ vg,
    const int* __restrict__ mg, char* __restrict__ ws)
{
    __shared__ unsigned short Tl[64 * 72];    // transposed V tile, padded stride
    const int bid = blockIdx.x;               // 0..1023
    const int t   = bid & 31;                 // key tile
    const int bh  = bid >> 5;
    const int b   = bh >> 4, h = bh & 15;
    const int tid = threadIdx.x;
    char* kpre = ws + (size_t)bh * PL_BYTES;
    char* vpre = ws + VOFF + (size_t)bh * PL_BYTES;

    // K: convert + swizzled store (thread -> 32B of output)
    {
        const int r  = tid >> 2;              // key row in tile
        const int c0 = (tid & 3) * 32;
        const int X  = (r & 7) << 4;
        const size_t grow = (((size_t)b * S_LEN + t * 64 + r) * NHEAD + h) * DHEAD;
        #pragma unroll
        for (int cc = 0; cc < 2; ++cc) {
            const int c  = c0 + 16 * cc;
            const int d0 = (c ^ X) >> 1;
            floatx4 f0 = *(const floatx4*)(kg + grow + d0);
            floatx4 f1 = *(const floatx4*)(kg + grow + d0 + 4);
            uintx4 pk = (uintx4){ f2bf(f0[0]) | (f2bf(f0[1]) << 16),
                                  f2bf(f0[2]) | (f2bf(f0[3]) << 16),
                                  f2bf(f1[0]) | (f2bf(f1[1]) << 16),
                                  f2bf(f1[2]) | (f2bf(f1[3]) << 16) };
            *(uintx4*)(kpre + t * 8192 + r * 128 + c) = pk;
        }
    }
    // V: load rows coalesced, zero pad-masked rows, transpose into LDS
    {
        const int key = tid >> 2;
        const int d0  = (tid & 3) * 16;
        const float vz = mg[(size_t)b * S_LEN + t * 64 + key] ? 1.f : 0.f;
        const size_t grow = (((size_t)b * S_LEN + t * 64 + key) * NHEAD + h) * DHEAD;
        #pragma unroll
        for (int q = 0; q < 4; ++q) {
            floatx4 f = *(const floatx4*)(vg + grow + d0 + 4 * q);
            #pragma unroll
            for (int ii = 0; ii < 4; ++ii)
                Tl[(d0 + 4 * q + ii) * 72 + key] = (unsigned short)f2bf(f[ii] * vz);
        }
    }
    __syncthreads();
    // V out: swizzled 16B chunks, keys gathered in interleaved storage order
    {
        const int d  = tid >> 2;
        const int c0 = (tid & 3) * 32;
        const int Xv = (d & 7) << 4;
        #pragma unroll
        for (int cc = 0; cc < 2; ++cc) {
            const int c   = c0 + 16 * cc;      // physical byte pos in 128B row
            const int pp0 = (c ^ Xv) >> 1;     // logical halfword pos (mult of 8)
            const int blk = pp0 >> 5;
            const int a   = (pp0 & 31) >> 3;
            unsigned short vals[8];
            #pragma unroll
            for (int i = 0; i < 8; ++i) {
                const int key = 32 * blk + ((i < 4) ? (4 * a + i) : (16 + 4 * a + i - 4));
                vals[i] = Tl[d * 72 + key];
            }
            *(uintx4*)(vpre + t * 8192 + d * 128 + c) = *(const uintx4*)vals;
        }
    }
    // mask frags: bf16 1.0/0.0 at slot (g,ks,i) matching pa's key map
    if (h == 0 && tid < 64) {
        const int key = tid;
        const int gg = (key >> 2) & 3, lo = key & 3;
        const int ks = key >> 5,      hi = (key >> 4) & 1;
        const unsigned short mv = mg[(size_t)b * S_LEN + t * 64 + key] ? 0x3F80 : 0;
        *(unsigned short*)(ws + MOFF + (size_t)b * 4096 + t * 128
                           + gg * 32 + ks * 16 + (4 * hi + lo) * 2) = mv;
    }
}

// ---------------------------------------------------------------------------
// Main: 128 q-rows/block, 4 waves (32 rows each, 2 q-groups), double-buffered
// K/V via global_load_lds; fixed-max (m=8) softmax: p = exp2(st) with -8
// folded into the accumulator init; denominator via mask-MFMA into dacc.
// ---------------------------------------------------------------------------
__global__ __launch_bounds__(256) void fa3_main(
    const float* __restrict__ qg, const char* __restrict__ ws,
    float* __restrict__ og)
{
    __shared__ unsigned short Qs[128 * DHEAD];       // 16 KB
    __shared__ unsigned short Ks[2][KB * DHEAD];     // 16 KB
    __shared__ unsigned short Vs[2][KB * DHEAD];     // 16 KB

    const int tid  = threadIdx.x;
    const int bid  = blockIdx.x;
    const int qb   = 15 - (bid >> 5);        // heavy q-blocks first
    const int bh   = bid & 31;
    const int b    = bh >> 4;
    const int h    = bh & 15;
    const int w    = tid >> 6;               // wave 0..3 -> q-rows [32w,32w+32)
    const int lane = tid & 63;
    const int g    = lane >> 4;
    const int lm   = lane & 15;
    const char* kpre = ws + (size_t)bh * PL_BYTES;
    const char* vpre = ws + VOFF + (size_t)bh * PL_BYTES;
    const char* mgf  = ws + MOFF + (size_t)b * 4096;
    const int nkt = (qb == 0) ? 2 : (2 * qb + 2);   // first 128 queries: keys [0,128) full

    // stage tile 0 (DMA overlaps the Q normalize below)
    const int soff = w * 1024 + lane * 16;
    #pragma unroll
    for (int rr = 0; rr < 2; ++rr) {
        GLOAD_LDS16(kpre + rr * 4096 + soff, (char*)&Ks[0][0] + rr * 4096 + w * 1024);
        GLOAD_LDS16(vpre + rr * 4096 + soff, (char*)&Vs[0][0] + rr * 4096 + w * 1024);
    }

    // stage Q: load fp32, L2-normalize * 0.125 * log2(e), bf16, swizzled
    #pragma unroll
    for (int rr = 0; rr < 2; ++rr) {
        const int r  = rr * 64 + (tid >> 2);  // q-row 0..127
        const int q0 = tid & 3;
        const float* src = qg + (((size_t)b * S_LEN + (size_t)qb * 128 + r) * NHEAD + h) * DHEAD + q0 * 16;
        floatx4 f0 = *(const floatx4*)(src + 0);
        floatx4 f1 = *(const floatx4*)(src + 4);
        floatx4 f2 = *(const floatx4*)(src + 8);
        floatx4 f3 = *(const floatx4*)(src + 12);
        float ssq = 0.f;
        #pragma unroll
        for (int i = 0; i < 4; ++i)
            ssq += f0[i]*f0[i] + f1[i]*f1[i] + f2[i]*f2[i] + f3[i]*f3[i];
        ssq += __shfl_xor(ssq, 1);
        ssq += __shfl_xor(ssq, 2);
        const float sc = (0.125f * LOG2E) / fmaxf(sqrtf(ssq), 1e-12f);
        float fv[16];
        #pragma unroll
        for (int i = 0; i < 4; ++i) { fv[i]=f0[i]; fv[4+i]=f1[i]; fv[8+i]=f2[i]; fv[12+i]=f3[i]; }
        unsigned pk[8];
        #pragma unroll
        for (int i = 0; i < 8; ++i)
            pk[i] = cvtpk(fv[2*i]*sc, fv[2*i+1]*sc);
        const int X = (r & 7) << 4;
        char* qp = (char*)Qs + r * 128;
        *(uintx4*)(qp + ((32*q0)      ^ X)) = (uintx4){pk[0],pk[1],pk[2],pk[3]};
        *(uintx4*)(qp + ((32*q0 + 16) ^ X)) = (uintx4){pk[4],pk[5],pk[6],pk[7]};
    }
    asm volatile("s_waitcnt vmcnt(0)" ::: "memory");   // tile-0 DMA complete
    __syncthreads();                                    // Qs + tile 0 visible

    // per-lane Q fragments: 2 q-groups (rows 32w+16grp+lm), contiguous k-map
    short8 qf[2][2];
    #pragma unroll
    for (int grp = 0; grp < 2; ++grp) {
        const int row = w * 32 + grp * 16 + lm;
        const int X = (row & 7) << 4;
        const char* base = (const char*)Qs + row * 128;
        #pragma unroll
        for (int ks = 0; ks < 2; ++ks)
            qf[grp][ks] = *(const short8*)(base + ((64*ks + 16*g) ^ X));
    }

    floatx4 oacc[2][4];
    floatx4 dacc[2];
    #pragma unroll
    for (int grp = 0; grp < 2; ++grp) {
        dacc[grp] = (floatx4){0.f,0.f,0.f,0.f};
        #pragma unroll
        for (int nt = 0; nt < 4; ++nt) oacc[grp][nt] = (floatx4){0.f,0.f,0.f,0.f};
    }
    const int qgl0 = qb * 128 + w * 32 + lm;           // grp0 q-row
    const int Xl = (lm & 7) << 4;

    int cur = 0;
    for (int kt = 0; kt < nkt; ++kt) {
        // issue next tile's DMA (hidden under this tile's compute)
        if (kt + 1 < nkt) {
            const size_t tb = (size_t)(kt + 1) * 8192;
            #pragma unroll
            for (int rr = 0; rr < 2; ++rr) {
                GLOAD_LDS16(kpre + tb + rr * 4096 + soff, (char*)&Ks[cur ^ 1][0] + rr * 4096 + w * 1024);
                GLOAD_LDS16(vpre + tb + rr * 4096 + soff, (char*)&Vs[cur ^ 1][0] + rr * 4096 + w * 1024);
            }
        }
        // mask fragments (global, broadcast per g-group, L2-resident)
        const short8 mf0 = *(const short8*)(mgf + kt * 128 + g * 32);
        const short8 mf1 = *(const short8*)(mgf + kt * 128 + g * 32 + 16);

        // ---- swapped QK^T for both q-groups; acc init -8 (fixed softmax max) ----
        floatx4 st[2][4];
        #pragma unroll
        for (int grp = 0; grp < 2; ++grp)
            #pragma unroll
            for (int mt = 0; mt < 4; ++mt) st[grp][mt] = (floatx4){-8.f,-8.f,-8.f,-8.f};
        const char* kbase = (const char*)Ks[cur] + lm * 128;
        __builtin_amdgcn_s_setprio(1);
        #pragma unroll
        for (int ks = 0; ks < 2; ++ks) {
            #pragma unroll
            for (int mt = 0; mt < 4; ++mt) {
                short8 kf = *(const short8*)(kbase + mt * 2048 + ((64*ks + 16*g) ^ Xl));
                st[0][mt] = mfma16(kf, qf[0][ks], st[0][mt]);
                st[1][mt] = mfma16(kf, qf[1][ks], st[1][mt]);
            }
        }
        __builtin_amdgcn_s_setprio(0);

        // ---- V B-frags (shared by both q-groups) ----
        short8 vf[4][2];
        {
            const char* vbase = (const char*)Vs[cur] + lm * 128;
            #pragma unroll
            for (int nt = 0; nt < 4; ++nt)
                #pragma unroll
                for (int ks = 0; ks < 2; ++ks)
                    vf[nt][ks] = *(const short8*)(vbase + nt * 2048 + ((64*ks + 16*g) ^ Xl));
        }

        // ---- causal (diagonal tiles only: kt in {2qb, 2qb+1}, qb>=1) ----
        const bool diag = (qb >= 1) && (kt >= 2 * qb);
        if (diag) {
            #pragma unroll
            for (int mt = 0; mt < 4; ++mt)
                #pragma unroll
                for (int j = 0; j < 4; ++j) {
                    const int kgl = kt * KB + mt * 16 + 4 * g + j;
                    if (kgl > qgl0)      st[0][mt][j] = -10000.f;
                    if (kgl > qgl0 + 16) st[1][mt][j] = -10000.f;
                }
        }

        // ---- p = exp2(st); pack; den-MFMA + PV-MFMA per group ----
        __builtin_amdgcn_s_setprio(1);
        #pragma unroll
        for (int grp = 0; grp < 2; ++grp) {
            float p[16];
            #pragma unroll
            for (int mt = 0; mt < 4; ++mt)
                #pragma unroll
                for (int j = 0; j < 4; ++j)
                    p[mt * 4 + j] = exp2f(st[grp][mt][j]);
            short8 pa[2];
            #pragma unroll
            for (int ks = 0; ks < 2; ++ks) {
                union { short8 s; uintx4 u; } pu;
                pu.u = (uintx4){ cvtpk(p[8*ks+0], p[8*ks+1]),
                                 cvtpk(p[8*ks+2], p[8*ks+3]),
                                 cvtpk(p[8*ks+4], p[8*ks+5]),
                                 cvtpk(p[8*ks+6], p[8*ks+7]) };
                pa[ks] = pu.s;
            }
            dacc[grp] = mfma16(pa[0], mf0, dacc[grp]);
            dacc[grp] = mfma16(pa[1], mf1, dacc[grp]);
            #pragma unroll
            for (int nt = 0; nt < 4; ++nt) {
                oacc[grp][nt] = mfma16(pa[0], vf[nt][0], oacc[grp][nt]);
                oacc[grp][nt] = mfma16(pa[1], vf[nt][1], oacc[grp][nt]);
            }
        }
        __builtin_amdgcn_s_setprio(0);

        asm volatile("s_waitcnt vmcnt(0)" ::: "memory");  // next tile's DMA done
        __syncthreads();
        cur ^= 1;
    }

    // ---- epilogue: O /= den (den already in O-layout, no shuffles) ----
    #pragma unroll
    for (int grp = 0; grp < 2; ++grp)
        #pragma unroll
        for (int j = 0; j < 4; ++j) {
            const float invj = 1.0f / dacc[grp][j];
            const int row = qb * 128 + w * 32 + grp * 16 + 4 * g + j;
            float* dst = og + (((size_t)b * S_LEN + row) * NHEAD + h) * DHEAD + lm;
            #pragma unroll
            for (int nt = 0; nt < 4; ++nt) dst[nt * 16] = oacc[grp][nt][j] * invj;
        }
}

// ---------------------------------------------------------------------------
// Fallback (round-2 kernel, known-good) if ws_size is too small.
// ---------------------------------------------------------------------------
__global__ __launch_bounds__(512) void fa3_fallback(
    const float* __restrict__ qg, const float* __restrict__ kg,
    const float* __restrict__ vg, const int* __restrict__ mg,
    float* __restrict__ og)
{
    __shared__ unsigned short Qs[128 * DHEAD];
    __shared__ unsigned short Ks2[KB * DHEAD];
    __shared__ unsigned short Vt[DHEAD * KB];
    __shared__ float Ms[KB];

    const int tid  = threadIdx.x;
    const int bid  = blockIdx.x;
    const int qb   = 15 - (bid >> 5);
    const int bh   = bid & 31;
    const int b    = bh >> 4;
    const int h    = bh & 15;
    const int w    = tid >> 6;
    const int lane = tid & 63;
    const int g    = lane >> 4;
    const int lm   = lane & 15;

    {
        const int r  = tid >> 2;
        const int q0 = tid & 3;
        const float* src = qg + (((size_t)b * S_LEN + (size_t)qb * 128 + r) * NHEAD + h) * DHEAD + q0 * 16;
        floatx4 f0 = *(const floatx4*)(src + 0);
        floatx4 f1 = *(const floatx4*)(src + 4);
        floatx4 f2 = *(const floatx4*)(src + 8);
        floatx4 f3 = *(const floatx4*)(src + 12);
        float ssq = 0.f;
        #pragma unroll
        for (int i = 0; i < 4; ++i)
            ssq += f0[i]*f0[i] + f1[i]*f1[i] + f2[i]*f2[i] + f3[i]*f3[i];
        ssq += __shfl_xor(ssq, 1);
        ssq += __shfl_xor(ssq, 2);
        const float sc = 0.125f / fmaxf(sqrtf(ssq), 1e-12f);
        float fv[16];
        #pragma unroll
        for (int i = 0; i < 4; ++i) { fv[i]=f0[i]; fv[4+i]=f1[i]; fv[8+i]=f2[i]; fv[12+i]=f3[i]; }
        unsigned pk[8];
        #pragma unroll
        for (int i = 0; i < 8; ++i)
            pk[i] = f2bf(fv[2*i]*sc) | (f2bf(fv[2*i+1]*sc) << 16);
        const int X = (r & 7) << 4;
        char* qp = (char*)Qs + r * 128;
        *(uintx4*)(qp + ((32*q0)      ^ X)) = (uintx4){pk[0],pk[1],pk[2],pk[3]};
        *(uintx4*)(qp + ((32*q0 + 16) ^ X)) = (uintx4){pk[4],pk[5],pk[6],pk[7]};
    }
    __syncthreads();

    short8 qf[2];
    {
        const int row = w * 16 + lm;
        const int X = (row & 7) << 4;
        const char* base = (const char*)Qs + row * 128;
        #pragma unroll
        for (int ks = 0; ks < 2; ++ks) {
            union { short8 s; uintx2 u[2]; } u;
            u.u[0] = *(const uintx2*)(base + ((64*ks + 8*g)      ^ X));
            u.u[1] = *(const uintx2*)(base + ((64*ks + 8*g + 32) ^ X));
            qf[ks] = u.s;
        }
    }

    floatx4 oacc[4];
    #pragma unroll
    for (int nt = 0; nt < 4; ++nt) oacc[nt] = (floatx4){0.f,0.f,0.f,0.f};
    float mrun = NEGINF, lrun = 0.f;
    const int q_glob = qb * 128 + w * 16 + lm;
    const int nkt = (qb == 0) ? 2 : (2 * qb + 2);

    for (int kt = 0; kt < nkt; ++kt) {
        const int kb0 = kt * KB;
        {
            const int r = tid >> 3;
            const int o = tid & 7;
            const size_t goff = (((size_t)b * S_LEN + kb0 + r) * NHEAD + h) * DHEAD + o * 8;
            floatx4 a0 = *(const floatx4*)(kg + goff);
            floatx4 a1 = *(const floatx4*)(kg + goff + 4);
            floatx4 c0 = *(const floatx4*)(vg + goff);
            floatx4 c1 = *(const floatx4*)(vg + goff + 4);
            uintx4 kw = (uintx4){ f2bf(a0[0]) | (f2bf(a0[1])<<16),
                                  f2bf(a0[2]) | (f2bf(a0[3])<<16),
                                  f2bf(a1[0]) | (f2bf(a1[1])<<16),
                                  f2bf(a1[2]) | (f2bf(a1[3])<<16) };
            *(uintx4*)((char*)Ks2 + r*128 + ((16*o) ^ ((r & 7) << 4))) = kw;
            float cv[8];
            #pragma unroll
            for (int i = 0; i < 4; ++i) { cv[i] = c0[i]; cv[4+i] = c1[i]; }
            #pragma unroll
            for (int i = 0; i < 8; ++i) {
                const int d = 8*o + i;
                Vt[d*64 + (r ^ (((i ^ o) & 7) << 3))] = (unsigned short)f2bf(cv[i]);
            }
            if (tid < KB) Ms[tid] = mg[(size_t)b * S_LEN + kb0 + tid] ? 0.f : NEGINF;
        }
        __syncthreads();

        floatx4 st[4];
        #pragma unroll
        for (int mt = 0; mt < 4; ++mt) st[mt] = (floatx4){0.f,0.f,0.f,0.f};
        #pragma unroll
        for (int ks = 0; ks < 2; ++ks) {
            #pragma unroll
            for (int mt = 0; mt < 4; ++mt) {
                const int row = mt * 16 + lm;
                const int X = (row & 7) << 4;
                const char* base = (const char*)Ks2 + row * 128;
                union { short8 s; uintx2 u[2]; } u;
                u.u[0] = *(const uintx2*)(base + ((64*ks + 8*g)      ^ X));
                u.u[1] = *(const uintx2*)(base + ((64*ks + 8*g + 32) ^ X));
                st[mt] = mfma16(u.s, qf[ks], st[mt]);
            }
        }

        const bool diag = (qb > 0) && (kt >= 2 * qb);
        float sv[16];
        #pragma unroll
        for (int mt = 0; mt < 4; ++mt) {
            #pragma unroll
            for (int j = 0; j < 4; ++j) {
                const int kl = mt * 16 + 4 * g + j;
                float s = st[mt][j] + Ms[kl];
                if (diag && (kb0 + kl > q_glob)) s = NEGINF;
                sv[mt * 4 + j] = s;
            }
        }

        float rmax = sv[0];
        #pragma unroll
        for (int i = 1; i < 16; ++i) rmax = fmaxf(rmax, sv[i]);
        rmax = fmaxf(rmax, __shfl_xor(rmax, 16));
        rmax = fmaxf(rmax, __shfl_xor(rmax, 32));
        const float mnew = fmaxf(mrun, rmax);
        const float cf = __expf(mrun - mnew);
        float p[16], psum = 0.f;
        #pragma unroll
        for (int i = 0; i < 16; ++i) { p[i] = __expf(sv[i] - mnew); psum += p[i]; }
        psum += __shfl_xor(psum, 16);
        psum += __shfl_xor(psum, 32);
        lrun = lrun * cf + psum;
        mrun = mnew;

        float cj[4];
        #pragma unroll
        for (int j = 0; j < 4; ++j) cj[j] = __shfl(cf, 20 * g + j);
        #pragma unroll
        for (int nt = 0; nt < 4; ++nt)
            #pragma unroll
            for (int j = 0; j < 4; ++j) oacc[nt][j] *= cj[j];

        short8 pa[2];
        #pragma unroll
        for (int ks = 0; ks < 2; ++ks)
            #pragma unroll
            for (int i = 0; i < 8; ++i)
                pa[ks][i] = (short)f2bf(p[(2*ks + (i>>2))*4 + (i&3)]);

        #pragma unroll
        for (int nt = 0; nt < 4; ++nt) {
            const int d = 16 * nt + lm;
            const int xz = (((d & 7) ^ ((d >> 3) & 7)) & 7) << 4;
            const char* vb = (const char*)Vt + d * 128;
            #pragma unroll
            for (int ks = 0; ks < 2; ++ks) {
                union { short8 s; uintx2 u[2]; } vu;
                vu.u[0] = *(const uintx2*)(vb + ((64*ks + 8*g)      ^ xz));
                vu.u[1] = *(const uintx2*)(vb + ((64*ks + 8*g + 32) ^ xz));
                oacc[nt] = mfma16(pa[ks], vu.s, oacc[nt]);
            }
        }
        __syncthreads();
    }

    const float inv = 1.0f / lrun;
    #pragma unroll
    for (int j = 0; j < 4; ++j) {
        const float invj = __shfl(inv, 20 * g + j);
        const int row = qb * 128 + w * 16 + 4 * g + j;
        float* dst = og + (((size_t)b * S_LEN + row) * NHEAD + h) * DHEAD + lm;
        #pragma unroll
        for (int nt = 0; nt < 4; ++nt) dst[nt * 16] = oacc[nt][j] * invj;
    }
}

extern "C" void kernel_launch(void* const* d_in, const int* in_sizes, int n_in,
                              void* d_out, int out_size, void* d_ws, size_t ws_size,
                              hipStream_t stream)
{
    const float* q = (const float*)d_in[0];
    const float* k = (const float*)d_in[1];
    const float* v = (const float*)d_in[2];
    const int*   m = (const int*)d_in[3];
    float* out = (float*)d_out;
    (void)in_sizes; (void)n_in; (void)out_size;
    if (ws_size >= WS_NEEDED) {
        prep_kernel<<<dim3(1024), dim3(256), 0, stream>>>(k, v, m, (char*)d_ws);
        fa3_main<<<dim3(512), dim3(256), 0, stream>>>(q, (const char*)d_ws, out);
    } else {
        fa3_fallback<<<dim3(512), dim3(512), 0, stream>>>(q, k, v, m, out);
    }
}

// Round 6
// 50.463 us; speedup vs baseline: 1.8149x; 1.2839x over previous
//
#include <hip/hip_runtime.h>
#include <stdint.h>

typedef __attribute__((ext_vector_type(8))) short short8;     // bf16x8 MFMA frag (4 VGPR)
typedef __attribute__((ext_vector_type(4))) float floatx4;
typedef __attribute__((ext_vector_type(4))) unsigned int uintx4;
typedef __attribute__((ext_vector_type(2))) unsigned int uintx2;

#define S_LEN 2048
#define NHEAD 16
#define DHEAD 64
#define KB    64
#define NTILE 32                              // S_LEN / KB
#define PL_BYTES (S_LEN * DHEAD * 2)          // 262144 bf16 bytes per (b,h) plane
#define VOFF  (2 * NHEAD * PL_BYTES)          // 8388608
#define MOFF  (2 * VOFF)                      // 16777216  (mask frags: 2 b x 4096 B)
#define WS_NEEDED ((size_t)MOFF + 2 * 4096)
#define NEGINF (-__builtin_inff())
#define LOG2E 1.4426950408889634f

#define GLOAD_LDS16(gp, lp) \
    __builtin_amdgcn_global_load_lds((const __attribute__((address_space(1))) unsigned int*)(gp), \
                                     (__attribute__((address_space(3))) unsigned int*)(lp), 16, 0, 0)

static __device__ __forceinline__ unsigned f2bf(float f) {
    union { float f; unsigned u; } w; w.f = f;
    return (w.u + 0x7FFFu + ((w.u >> 16) & 1u)) >> 16;   // RNE f32->bf16
}

static __device__ __forceinline__ unsigned cvtpk(float lo, float hi) {
    unsigned r;
    asm("v_cvt_pk_bf16_f32 %0, %1, %2" : "=v"(r) : "v"(lo), "v"(hi));
    return r;                                             // [hi_bf16 | lo_bf16]
}

static __device__ __forceinline__ floatx4 mfma16(short8 a, short8 b, floatx4 c) {
    return __builtin_amdgcn_mfma_f32_16x16x32_bf16(a, b, c, 0, 0, 0);
}

// ---------------------------------------------------------------------------
// Prepass (unchanged from round 5): K -> bf16 row-major pre-swizzled;
// V -> bf16 TRANSPOSED [d][pkey] (per-32 key interleave
// p=8a+i -> key 16(i>>2)+4a+(i&3)), pad-masked V rows ZEROED;
// mask -> bf16 0/1 vector in PV-fragment order (128 B per (b,tile)).
// Swizzle (K,V planes): byte ^= (row&7)<<4 within 128B rows.
// ---------------------------------------------------------------------------
__global__ __launch_bounds__(256) void prep_kernel(
    const float* __restrict__ kg, const float* __restrict__ vg,
    const int* __restrict__ mg, char* __restrict__ ws)
{
    __shared__ unsigned short Tl[64 * 72];    // transposed V tile, padded stride
    const int bid = blockIdx.x;               // 0..1023
    const int t   = bid & 31;                 // key tile
    const int bh  = bid >> 5;
    const int b   = bh >> 4, h = bh & 15;
    const int tid = threadIdx.x;
    char* kpre = ws + (size_t)bh * PL_BYTES;
    char* vpre = ws + VOFF + (size_t)bh * PL_BYTES;

    // K: convert + swizzled store (thread -> 32B of output)
    {
        const int r  = tid >> 2;              // key row in tile
        const int c0 = (tid & 3) * 32;
        const int X  = (r & 7) << 4;
        const size_t grow = (((size_t)b * S_LEN + t * 64 + r) * NHEAD + h) * DHEAD;
        #pragma unroll
        for (int cc = 0; cc < 2; ++cc) {
            const int c  = c0 + 16 * cc;
            const int d0 = (c ^ X) >> 1;
            floatx4 f0 = *(const floatx4*)(kg + grow + d0);
            floatx4 f1 = *(const floatx4*)(kg + grow + d0 + 4);
            uintx4 pk = (uintx4){ f2bf(f0[0]) | (f2bf(f0[1]) << 16),
                                  f2bf(f0[2]) | (f2bf(f0[3]) << 16),
                                  f2bf(f1[0]) | (f2bf(f1[1]) << 16),
                                  f2bf(f1[2]) | (f2bf(f1[3]) << 16) };
            *(uintx4*)(kpre + t * 8192 + r * 128 + c) = pk;
        }
    }
    // V: load rows coalesced, zero pad-masked rows, transpose into LDS
    {
        const int key = tid >> 2;
        const int d0  = (tid & 3) * 16;
        const float vz = mg[(size_t)b * S_LEN + t * 64 + key] ? 1.f : 0.f;
        const size_t grow = (((size_t)b * S_LEN + t * 64 + key) * NHEAD + h) * DHEAD;
        #pragma unroll
        for (int q = 0; q < 4; ++q) {
            floatx4 f = *(const floatx4*)(vg + grow + d0 + 4 * q);
            #pragma unroll
            for (int ii = 0; ii < 4; ++ii)
                Tl[(d0 + 4 * q + ii) * 72 + key] = (unsigned short)f2bf(f[ii] * vz);
        }
    }
    __syncthreads();
    // V out: swizzled 16B chunks, keys gathered in interleaved storage order
    {
        const int d  = tid >> 2;
        const int c0 = (tid & 3) * 32;
        const int Xv = (d & 7) << 4;
        #pragma unroll
        for (int cc = 0; cc < 2; ++cc) {
            const int c   = c0 + 16 * cc;      // physical byte pos in 128B row
            const int pp0 = (c ^ Xv) >> 1;     // logical halfword pos (mult of 8)
            const int blk = pp0 >> 5;
            const int a   = (pp0 & 31) >> 3;
            unsigned short vals[8];
            #pragma unroll
            for (int i = 0; i < 8; ++i) {
                const int key = 32 * blk + ((i < 4) ? (4 * a + i) : (16 + 4 * a + i - 4));
                vals[i] = Tl[d * 72 + key];
            }
            *(uintx4*)(vpre + t * 8192 + d * 128 + c) = *(const uintx4*)vals;
        }
    }
    // mask frags: bf16 1.0/0.0 at slot (g,ks,i) matching pa's key map
    if (h == 0 && tid < 64) {
        const int key = tid;
        const int gg = (key >> 2) & 3, lo = key & 3;
        const int ks = key >> 5,      hi = (key >> 4) & 1;
        const unsigned short mv = mg[(size_t)b * S_LEN + t * 64 + key] ? 0x3F80 : 0;
        *(unsigned short*)(ws + MOFF + (size_t)b * 4096 + t * 128
                           + gg * 32 + ks * 16 + (4 * hi + lo) * 2) = mv;
    }
}

// ---------------------------------------------------------------------------
// Main: 128 q-rows/block, 8 waves (wave = 32 q-rows x 32-key-half),
// double-buffered K/V via global_load_lds; fixed-max softmax (m=8, folded
// into acc init); den via mask-MFMA; cross-key-half combine once at end.
// Balanced bid->(b,h,qb) pairing so co-resident blocks sum to ~const tiles.
// ---------------------------------------------------------------------------
__global__ __launch_bounds__(512, 4) void fa3_main(
    const float* __restrict__ qg, const char* __restrict__ ws,
    float* __restrict__ og)
{
    __shared__ char smem[49152];
    unsigned short* Qs = (unsigned short*)smem;          // 16 KB [128*64]
    char* KsB = smem + 16384;                            // 2 x 8 KB (dbuf)
    char* VsB = smem + 32768;                            // 2 x 8 KB (dbuf)

    const int tid  = threadIdx.x;
    const int bid  = blockIdx.x;
    // balanced pairing: bid and bid+256 land on the same CU (XCD rr model)
    // and get qb = 15-r / r  -> per-CU tile sum ~const; bid&7 == bh&7 keeps
    // same-(b,h) blocks on one XCD for L2 locality.
    const int b    = bid >> 8;
    const int bh   = (b << 4) | (bid & 15);
    const int rpair= (bid >> 4) & 15;
    const int qb   = b ? rpair : 15 - rpair;
    const int h    = bh & 15;
    const int w    = tid >> 6;               // wave 0..7
    const int lane = tid & 63;
    const int g    = lane >> 4;
    const int lm   = lane & 15;
    const int kh   = w >> 2;                 // key half 0/1 (32 keys)
    const int wq   = w & 3;                  // q sub-block: rows [32wq, 32wq+32)
    const char* kpre = ws + (size_t)bh * PL_BYTES;
    const char* vpre = ws + VOFF + (size_t)bh * PL_BYTES;
    const char* mgf  = ws + MOFF + (size_t)b * 4096;
    const int nkt = (qb == 0) ? 2 : (2 * qb + 2);

    // stage tile 0 (one 16B DMA per thread per plane)
    GLOAD_LDS16(kpre + tid * 16, KsB + tid * 16);
    GLOAD_LDS16(vpre + tid * 16, VsB + tid * 16);

    // stage Q: load fp32, L2-normalize * 0.125 * log2(e), bf16, swizzled
    {
        const int r  = tid >> 2;             // q-row 0..127
        const int q0 = tid & 3;
        const float* src = qg + (((size_t)b * S_LEN + (size_t)qb * 128 + r) * NHEAD + h) * DHEAD + q0 * 16;
        floatx4 f0 = *(const floatx4*)(src + 0);
        floatx4 f1 = *(const floatx4*)(src + 4);
        floatx4 f2 = *(const floatx4*)(src + 8);
        floatx4 f3 = *(const floatx4*)(src + 12);
        float ssq = 0.f;
        #pragma unroll
        for (int i = 0; i < 4; ++i)
            ssq += f0[i]*f0[i] + f1[i]*f1[i] + f2[i]*f2[i] + f3[i]*f3[i];
        ssq += __shfl_xor(ssq, 1);
        ssq += __shfl_xor(ssq, 2);
        const float sc = (0.125f * LOG2E) / fmaxf(sqrtf(ssq), 1e-12f);
        float fv[16];
        #pragma unroll
        for (int i = 0; i < 4; ++i) { fv[i]=f0[i]; fv[4+i]=f1[i]; fv[8+i]=f2[i]; fv[12+i]=f3[i]; }
        unsigned pk[8];
        #pragma unroll
        for (int i = 0; i < 8; ++i)
            pk[i] = cvtpk(fv[2*i]*sc, fv[2*i+1]*sc);
        const int X = (r & 7) << 4;
        char* qp = (char*)Qs + r * 128;
        *(uintx4*)(qp + ((32*q0)      ^ X)) = (uintx4){pk[0],pk[1],pk[2],pk[3]};
        *(uintx4*)(qp + ((32*q0 + 16) ^ X)) = (uintx4){pk[4],pk[5],pk[6],pk[7]};
    }
    asm volatile("s_waitcnt vmcnt(0)" ::: "memory");   // tile-0 DMA complete
    __syncthreads();                                    // Qs + tile 0 visible

    const int Xl = (lm & 7) << 4;
    // per-lane Q fragments: 2 q-groups (rows 32wq+16grp+lm), contiguous d-map
    short8 qf[2][2];
    #pragma unroll
    for (int grp = 0; grp < 2; ++grp) {
        const int row = wq * 32 + grp * 16 + lm;
        const char* base = (const char*)Qs + row * 128;
        #pragma unroll
        for (int ksd = 0; ksd < 2; ++ksd)
            qf[grp][ksd] = *(const short8*)(base + ((64*ksd + 16*g) ^ Xl));
    }

    floatx4 oacc[2][4];
    floatx4 dacc[2];
    #pragma unroll
    for (int grp = 0; grp < 2; ++grp) {
        dacc[grp] = (floatx4){0.f,0.f,0.f,0.f};
        #pragma unroll
        for (int nt = 0; nt < 4; ++nt) oacc[grp][nt] = (floatx4){0.f,0.f,0.f,0.f};
    }
    const int qgl0 = qb * 128 + wq * 32 + lm;          // grp0 q-row

    int cur = 0;
    for (int kt = 0; kt < nkt; ++kt) {
        // issue next tile's DMA (hidden under this tile's compute)
        if (kt + 1 < nkt) {
            const size_t tb = (size_t)(kt + 1) * 8192;
            GLOAD_LDS16(kpre + tb + tid * 16, KsB + (cur ^ 1) * 8192 + tid * 16);
            GLOAD_LDS16(vpre + tb + tid * 16, VsB + (cur ^ 1) * 8192 + tid * 16);
        }
        // mask fragment for this wave's 32 keys (uniform per (g,kh), L2-hit)
        const short8 mf = *(const short8*)(mgf + kt * 128 + g * 32 + kh * 16);

        // ---- swapped QK^T on this wave's key half; acc init -8 ----
        floatx4 st[2][2];
        #pragma unroll
        for (int grp = 0; grp < 2; ++grp)
            #pragma unroll
            for (int mt = 0; mt < 2; ++mt) st[grp][mt] = (floatx4){-8.f,-8.f,-8.f,-8.f};
        const char* kbase = KsB + cur * 8192 + kh * 4096 + lm * 128;
        __builtin_amdgcn_s_setprio(1);
        #pragma unroll
        for (int ksd = 0; ksd < 2; ++ksd) {
            #pragma unroll
            for (int mt = 0; mt < 2; ++mt) {
                short8 kf = *(const short8*)(kbase + mt * 2048 + ((64*ksd + 16*g) ^ Xl));
                st[0][mt] = mfma16(kf, qf[0][ksd], st[0][mt]);
                st[1][mt] = mfma16(kf, qf[1][ksd], st[1][mt]);
            }
        }
        __builtin_amdgcn_s_setprio(0);

        // ---- causal (diagonal tiles only: kt in {2qb, 2qb+1}, qb>=1) ----
        if ((qb >= 1) && (kt >= 2 * qb)) {
            #pragma unroll
            for (int mt = 0; mt < 2; ++mt)
                #pragma unroll
                for (int j = 0; j < 4; ++j) {
                    const int kgl = kt * KB + kh * 32 + mt * 16 + 4 * g + j;
                    if (kgl > qgl0)      st[0][mt][j] = -10000.f;
                    if (kgl > qgl0 + 16) st[1][mt][j] = -10000.f;
                }
        }

        // ---- p = exp2(st); pack; den-MFMA + PV-MFMA ----
        short8 pa[2];
        #pragma unroll
        for (int grp = 0; grp < 2; ++grp) {
            float p[8];
            #pragma unroll
            for (int mt = 0; mt < 2; ++mt)
                #pragma unroll
                for (int j = 0; j < 4; ++j)
                    p[mt * 4 + j] = exp2f(st[grp][mt][j]);
            union { short8 s; uintx4 u; } pu;
            pu.u = (uintx4){ cvtpk(p[0], p[1]), cvtpk(p[2], p[3]),
                             cvtpk(p[4], p[5]), cvtpk(p[6], p[7]) };
            pa[grp] = pu.s;
        }
        __builtin_amdgcn_s_setprio(1);
        dacc[0] = mfma16(pa[0], mf, dacc[0]);
        dacc[1] = mfma16(pa[1], mf, dacc[1]);
        {
            const char* vbase = VsB + cur * 8192 + lm * 128;
            #pragma unroll
            for (int nt = 0; nt < 4; ++nt) {
                short8 vf = *(const short8*)(vbase + nt * 2048 + ((64*kh + 16*g) ^ Xl));
                oacc[0][nt] = mfma16(pa[0], vf, oacc[0][nt]);
                oacc[1][nt] = mfma16(pa[1], vf, oacc[1][nt]);
            }
        }
        __builtin_amdgcn_s_setprio(0);

        asm volatile("s_waitcnt vmcnt(0)" ::: "memory");  // next tile's DMA done
        __syncthreads();
        cur ^= 1;
    }

    // ---- combine key halves: kh=1 waves dump partials to LDS, kh=0 sum ----
    floatx4* rbuf = (floatx4*)(smem + 16384);   // 32 KB (reuse K/V buffers)
    float*   dbuf = (float*)smem;               // 512 B (reuse Qs)
    if (kh == 1) {
        const int tpos = (w - 4) * 64 + lane;   // 0..255
        #pragma unroll
        for (int grp = 0; grp < 2; ++grp) {
            #pragma unroll
            for (int nt = 0; nt < 4; ++nt)
                rbuf[(grp * 4 + nt) * 256 + tpos] = oacc[grp][nt];
            if (lm == 0) {
                #pragma unroll
                for (int j = 0; j < 4; ++j)
                    dbuf[wq * 32 + grp * 16 + 4 * g + j] = dacc[grp][j];
            }
        }
    }
    __syncthreads();
    if (kh == 0) {
        const int tpos = w * 64 + lane;
        #pragma unroll
        for (int grp = 0; grp < 2; ++grp) {
            #pragma unroll
            for (int nt = 0; nt < 4; ++nt)
                oacc[grp][nt] += rbuf[(grp * 4 + nt) * 256 + tpos];
            #pragma unroll
            for (int j = 0; j < 4; ++j) {
                const float den = dacc[grp][j] + dbuf[wq * 32 + grp * 16 + 4 * g + j];
                const float invj = 1.0f / den;
                const int row = qb * 128 + wq * 32 + grp * 16 + 4 * g + j;
                float* dst = og + (((size_t)b * S_LEN + row) * NHEAD + h) * DHEAD + lm;
                #pragma unroll
                for (int nt = 0; nt < 4; ++nt) dst[nt * 16] = oacc[grp][nt][j] * invj;
            }
        }
    }
}

// ---------------------------------------------------------------------------
// Fallback (round-2 kernel, known-good) if ws_size is too small.
// ---------------------------------------------------------------------------
__global__ __launch_bounds__(512) void fa3_fallback(
    const float* __restrict__ qg, const float* __restrict__ kg,
    const float* __restrict__ vg, const int* __restrict__ mg,
    float* __restrict__ og)
{
    __shared__ unsigned short Qs[128 * DHEAD];
    __shared__ unsigned short Ks2[KB * DHEAD];
    __shared__ unsigned short Vt[DHEAD * KB];
    __shared__ float Ms[KB];

    const int tid  = threadIdx.x;
    const int bid  = blockIdx.x;
    const int qb   = 15 - (bid >> 5);
    const int bh   = bid & 31;
    const int b    = bh >> 4;
    const int h    = bh & 15;
    const int w    = tid >> 6;
    const int lane = tid & 63;
    const int g    = lane >> 4;
    const int lm   = lane & 15;

    {
        const int r  = tid >> 2;
        const int q0 = tid & 3;
        const float* src = qg + (((size_t)b * S_LEN + (size_t)qb * 128 + r) * NHEAD + h) * DHEAD + q0 * 16;
        floatx4 f0 = *(const floatx4*)(src + 0);
        floatx4 f1 = *(const floatx4*)(src + 4);
        floatx4 f2 = *(const floatx4*)(src + 8);
        floatx4 f3 = *(const floatx4*)(src + 12);
        float ssq = 0.f;
        #pragma unroll
        for (int i = 0; i < 4; ++i)
            ssq += f0[i]*f0[i] + f1[i]*f1[i] + f2[i]*f2[i] + f3[i]*f3[i];
        ssq += __shfl_xor(ssq, 1);
        ssq += __shfl_xor(ssq, 2);
        const float sc = 0.125f / fmaxf(sqrtf(ssq), 1e-12f);
        float fv[16];
        #pragma unroll
        for (int i = 0; i < 4; ++i) { fv[i]=f0[i]; fv[4+i]=f1[i]; fv[8+i]=f2[i]; fv[12+i]=f3[i]; }
        unsigned pk[8];
        #pragma unroll
        for (int i = 0; i < 8; ++i)
            pk[i] = f2bf(fv[2*i]*sc) | (f2bf(fv[2*i+1]*sc) << 16);
        const int X = (r & 7) << 4;
        char* qp = (char*)Qs + r * 128;
        *(uintx4*)(qp + ((32*q0)      ^ X)) = (uintx4){pk[0],pk[1],pk[2],pk[3]};
        *(uintx4*)(qp + ((32*q0 + 16) ^ X)) = (uintx4){pk[4],pk[5],pk[6],pk[7]};
    }
    __syncthreads();

    short8 qf[2];
    {
        const int row = w * 16 + lm;
        const int X = (row & 7) << 4;
        const char* base = (const char*)Qs + row * 128;
        #pragma unroll
        for (int ks = 0; ks < 2; ++ks) {
            union { short8 s; uintx2 u[2]; } u;
            u.u[0] = *(const uintx2*)(base + ((64*ks + 8*g)      ^ X));
            u.u[1] = *(const uintx2*)(base + ((64*ks + 8*g + 32) ^ X));
            qf[ks] = u.s;
        }
    }

    floatx4 oacc[4];
    #pragma unroll
    for (int nt = 0; nt < 4; ++nt) oacc[nt] = (floatx4){0.f,0.f,0.f,0.f};
    float mrun = NEGINF, lrun = 0.f;
    const int q_glob = qb * 128 + w * 16 + lm;
    const int nkt = (qb == 0) ? 2 : (2 * qb + 2);

    for (int kt = 0; kt < nkt; ++kt) {
        const int kb0 = kt * KB;
        {
            const int r = tid >> 3;
            const int o = tid & 7;
            const size_t goff = (((size_t)b * S_LEN + kb0 + r) * NHEAD + h) * DHEAD + o * 8;
            floatx4 a0 = *(const floatx4*)(kg + goff);
            floatx4 a1 = *(const floatx4*)(kg + goff + 4);
            floatx4 c0 = *(const floatx4*)(vg + goff);
            floatx4 c1 = *(const floatx4*)(vg + goff + 4);
            uintx4 kw = (uintx4){ f2bf(a0[0]) | (f2bf(a0[1])<<16),
                                  f2bf(a0[2]) | (f2bf(a0[3])<<16),
                                  f2bf(a1[0]) | (f2bf(a1[1])<<16),
                                  f2bf(a1[2]) | (f2bf(a1[3])<<16) };
            *(uintx4*)((char*)Ks2 + r*128 + ((16*o) ^ ((r & 7) << 4))) = kw;
            float cv[8];
            #pragma unroll
            for (int i = 0; i < 4; ++i) { cv[i] = c0[i]; cv[4+i] = c1[i]; }
            #pragma unroll
            for (int i = 0; i < 8; ++i) {
                const int d = 8*o + i;
                Vt[d*64 + (r ^ (((i ^ o) & 7) << 3))] = (unsigned short)f2bf(cv[i]);
            }
            if (tid < KB) Ms[tid] = mg[(size_t)b * S_LEN + kb0 + tid] ? 0.f : NEGINF;
        }
        __syncthreads();

        floatx4 st[4];
        #pragma unroll
        for (int mt = 0; mt < 4; ++mt) st[mt] = (floatx4){0.f,0.f,0.f,0.f};
        #pragma unroll
        for (int ks = 0; ks < 2; ++ks) {
            #pragma unroll
            for (int mt = 0; mt < 4; ++mt) {
                const int row = mt * 16 + lm;
                const int X = (row & 7) << 4;
                const char* base = (const char*)Ks2 + row * 128;
                union { short8 s; uintx2 u[2]; } u;
                u.u[0] = *(const uintx2*)(base + ((64*ks + 8*g)      ^ X));
                u.u[1] = *(const uintx2*)(base + ((64*ks + 8*g + 32) ^ X));
                st[mt] = mfma16(u.s, qf[ks], st[mt]);
            }
        }

        const bool diag = (qb > 0) && (kt >= 2 * qb);
        float sv[16];
        #pragma unroll
        for (int mt = 0; mt < 4; ++mt) {
            #pragma unroll
            for (int j = 0; j < 4; ++j) {
                const int kl = mt * 16 + 4 * g + j;
                float s = st[mt][j] + Ms[kl];
                if (diag && (kb0 + kl > q_glob)) s = NEGINF;
                sv[mt * 4 + j] = s;
            }
        }

        float rmax = sv[0];
        #pragma unroll
        for (int i = 1; i < 16; ++i) rmax = fmaxf(rmax, sv[i]);
        rmax = fmaxf(rmax, __shfl_xor(rmax, 16));
        rmax = fmaxf(rmax, __shfl_xor(rmax, 32));
        const float mnew = fmaxf(mrun, rmax);
        const float cf = __expf(mrun - mnew);
        float p[16], psum = 0.f;
        #pragma unroll
        for (int i = 0; i < 16; ++i) { p[i] = __expf(sv[i] - mnew); psum += p[i]; }
        psum += __shfl_xor(psum, 16);
        psum += __shfl_xor(psum, 32);
        lrun = lrun * cf + psum;
        mrun = mnew;

        float cj[4];
        #pragma unroll
        for (int j = 0; j < 4; ++j) cj[j] = __shfl(cf, 20 * g + j);
        #pragma unroll
        for (int nt = 0; nt < 4; ++nt)
            #pragma unroll
            for (int j = 0; j < 4; ++j) oacc[nt][j] *= cj[j];

        short8 pa[2];
        #pragma unroll
        for (int ks = 0; ks < 2; ++ks)
            #pragma unroll
            for (int i = 0; i < 8; ++i)
                pa[ks][i] = (short)f2bf(p[(2*ks + (i>>2))*4 + (i&3)]);

        #pragma unroll
        for (int nt = 0; nt < 4; ++nt) {
            const int d = 16 * nt + lm;
            const int xz = (((d & 7) ^ ((d >> 3) & 7)) & 7) << 4;
            const char* vb = (const char*)Vt + d * 128;
            #pragma unroll
            for (int ks = 0; ks < 2; ++ks) {
                union { short8 s; uintx2 u[2]; } vu;
                vu.u[0] = *(const uintx2*)(vb + ((64*ks + 8*g)      ^ xz));
                vu.u[1] = *(const uintx2*)(vb + ((64*ks + 8*g + 32) ^ xz));
                oacc[nt] = mfma16(pa[ks], vu.s, oacc[nt]);
            }
        }
        __syncthreads();
    }

    const float inv = 1.0f / lrun;
    #pragma unroll
    for (int j = 0; j < 4; ++j) {
        const float invj = __shfl(inv, 20 * g + j);
        const int row = qb * 128 + w * 16 + 4 * g + j;
        float* dst = og + (((size_t)b * S_LEN + row) * NHEAD + h) * DHEAD + lm;
        #pragma unroll
        for (int nt = 0; nt < 4; ++nt) dst[nt * 16] = oacc[nt][j] * invj;
    }
}

extern "C" void kernel_launch(void* const* d_in, const int* in_sizes, int n_in,
                              void* d_out, int out_size, void* d_ws, size_t ws_size,
                              hipStream_t stream)
{
    const float* q = (const float*)d_in[0];
    const float* k = (const float*)d_in[1];
    const float* v = (const float*)d_in[2];
    const int*   m = (const int*)d_in[3];
    float* out = (float*)d_out;
    (void)in_sizes; (void)n_in; (void)out_size;
    if (ws_size >= WS_NEEDED) {
        prep_kernel<<<dim3(1024), dim3(256), 0, stream>>>(k, v, m, (char*)d_ws);
        fa3_main<<<dim3(512), dim3(512), 0, stream>>>(q, (const char*)d_ws, out);
    } else {
        fa3_fallback<<<dim3(512), dim3(512), 0, stream>>>(q, k, v, m, out);
    }
}